// Round 1
// baseline (946.544 us; speedup 1.0000x reference)
//
#include <hip/hip_runtime.h>

#define BATCH 2
#define NBOX 500
#define CH 512
#define HFD 25
#define IW 26
#define IRC (IW * IW)      // 676
#define PPOOL 7
#define NP 49
#define NCLS 20
#define NO 101             // 80 loc + 21 score
#define OP 104             // padded outputs
#define OHALF 52
#define KDIM 25088
#define FDIM 4096
#define FSPLIT 4
#define FCHUNK (FDIM / FSPLIT)

// ---------------- Lt[f][o] = L[o][f] (L = [l_w; s_w]), zero-padded to OP ----
__global__ void k_lt(const float* __restrict__ lw, const float* __restrict__ sw,
                     float* __restrict__ Lt) {
    int e = blockIdx.x * blockDim.x + threadIdx.x;   // over OP*FDIM
    if (e >= OP * FDIM) return;
    int o = e / FDIM, f = e - o * FDIM;
    float v = 0.f;
    if (o < 80) v = lw[o * FDIM + f];
    else if (o < NO) v = sw[(o - 80) * FDIM + f];
    Lt[f * OP + o] = v;
}

// ---------------- integral image, c-major: I[b][ch][r*26+c] ----------------
__global__ void k_integral(const float* __restrict__ fm, float* __restrict__ I) {
    int gtid = blockIdx.x * blockDim.x + threadIdx.x;
    int wid = gtid >> 6;
    int lane = gtid & 63;
    if (wid >= BATCH * CH) return;
    const float* src = fm + (size_t)wid * (HFD * HFD);
    float* dst = I + (size_t)wid * IRC;
    if (lane < IW) dst[lane] = 0.f;                   // row 0
    if (lane >= 1 && lane < IW) dst[lane * IW] = 0.f; // col 0
    int c = lane;
    float acc = 0.f;
    for (int r = 0; r < HFD; ++r) {
        float v = (c < HFD) ? src[r * HFD + c] : 0.f;
        #pragma unroll
        for (int d = 1; d < 32; d <<= 1) {
            float t = __shfl_up(v, d, 64);
            if (lane >= d) v += t;
        }
        acc += v;   // acc = I[r+1][c+1]
        if (c < HFD) dst[(r + 1) * IW + (c + 1)] = acc;
    }
}

// ---------------- bias'[o] = L[o]·fc_b + {l_b|s_b}[o] ----------------------
__global__ void k_bias(const float* __restrict__ lw, const float* __restrict__ sw,
                       const float* __restrict__ fcb, const float* __restrict__ lb,
                       const float* __restrict__ sb, float* __restrict__ bias) {
    int o = blockIdx.x;
    __shared__ float red[256];
    float s = 0.f;
    if (o < NO) {
        const float* row = (o < 80) ? (lw + (size_t)o * FDIM) : (sw + (size_t)(o - 80) * FDIM);
        for (int f = threadIdx.x; f < FDIM; f += 256) s += row[f] * fcb[f];
    }
    red[threadIdx.x] = s;
    __syncthreads();
    for (int st = 128; st > 0; st >>= 1) {
        if ((int)threadIdx.x < st) red[threadIdx.x] += red[threadIdx.x + st];
        __syncthreads();
    }
    if (threadIdx.x == 0) {
        float bv = 0.f;
        if (o < 80) bv = red[0] + lb[o];
        else if (o < NO) bv = red[0] + sb[o - 80];
        bias[o] = bv;
    }
}

// ---------------- Wc partials: Wpart[s][k][o] = sum_{f in seg s} Lt[f][o]*W1[f][k]
// grid (2, 98, 4): x = o-half (adjacent blocks share W1 reads -> L2 hit),
// y = k-block, z = f-segment. Thread owns one k column, 52 fp32 accumulators.
// Lt reads are wave-uniform -> compiler emits s_load (SGPR operand FMAs).
__global__ void __launch_bounds__(256) k_wc(const float* __restrict__ W1,
                                            const float* __restrict__ Lt,
                                            float* __restrict__ Wpart) {
    int z = blockIdx.x;                  // 0..1  o-half
    int k = blockIdx.y * 256 + threadIdx.x;
    int s = blockIdx.z;                  // 0..3  f-segment
    const float* lt = Lt + z * OHALF;
    int f0 = s * FCHUNK, f1 = f0 + FCHUNK;
    float acc[OHALF];
    #pragma unroll
    for (int j = 0; j < OHALF; ++j) acc[j] = 0.f;
    float w = W1[(size_t)f0 * KDIM + k];
    for (int f = f0; f < f1; ++f) {
        float wn = (f + 1 < f1) ? W1[(size_t)(f + 1) * KDIM + k] : 0.f;
        const float* ltf = lt + (size_t)f * OP;
        #pragma unroll
        for (int j = 0; j < OHALF; ++j) acc[j] += ltf[j] * w;
        w = wn;
    }
    float4* dst = (float4*)(Wpart + ((size_t)s * KDIM + k) * OP + z * OHALF);
    #pragma unroll
    for (int j = 0; j < OHALF / 4; ++j)
        dst[j] = make_float4(acc[4 * j], acc[4 * j + 1], acc[4 * j + 2], acc[4 * j + 3]);
}

// ---------------- reduce f-segments -> Wc[k][o] ----------------------------
__global__ void k_reduce(const float* __restrict__ Wpart, float* __restrict__ Wc) {
    int e = blockIdx.x * 256 + threadIdx.x;
    if (e >= KDIM * OP) return;
    const size_t S = (size_t)KDIM * OP;
    Wc[e] = Wpart[e] + Wpart[e + S] + Wpart[e + 2 * S] + Wpart[e + 3 * S];
}

// ---------------- H[b][p][rc][o] = sum_c' Wc[c'*49+p][o] * I[b][c'][rc] ----
__global__ void __launch_bounds__(256) k_h(const float* __restrict__ I,
                                           const float* __restrict__ Wc,
                                           float* __restrict__ H) {
    int rc = blockIdx.x * 256 + threadIdx.x;
    if (rc >= IRC) return;
    int p = blockIdx.y;
    int b = blockIdx.z >> 1, z = blockIdx.z & 1;
    const float* Ib = I + (size_t)b * CH * IRC + rc;
    const float* wc = Wc + (size_t)p * OP + z * OHALF;
    float acc[OHALF];
    #pragma unroll
    for (int j = 0; j < OHALF; ++j) acc[j] = 0.f;
    float v = Ib[0];
    for (int c = 0; c < CH; ++c) {
        float vn = (c + 1 < CH) ? Ib[(size_t)(c + 1) * IRC] : 0.f;
        const float* wcc = wc + (size_t)c * NP * OP;
        #pragma unroll
        for (int j = 0; j < OHALF; ++j) acc[j] += wcc[j] * v;
        v = vn;
    }
    float4* dst = (float4*)(H + (((size_t)(b * NP + p)) * IRC + rc) * OP + z * OHALF);
    #pragma unroll
    for (int j = 0; j < OHALF / 4; ++j)
        dst[j] = make_float4(acc[4 * j], acc[4 * j + 1], acc[4 * j + 2], acc[4 * j + 3]);
}

// ---------------- per-box gather + bias + argmax + outputs -----------------
__global__ void __launch_bounds__(128) k_out(const float* __restrict__ boxes,
                                             const float* __restrict__ H,
                                             const float* __restrict__ bias,
                                             float* __restrict__ out) {
    int n = blockIdx.x, b = blockIdx.y;
    int t = threadIdx.x;
    __shared__ int srs[PPOOL], sre[PPOOL], scs[PPOOL], sce[PPOOL];
    __shared__ float sinv[NP];
    __shared__ float sl[NO];
    __shared__ int smi;
    const float* bx = boxes + ((size_t)b * NBOX + n) * 4;
    if (t < PPOOL) {
        int r0 = (int)(bx[0] / 32.0f);
        int c0 = (int)(bx[1] / 32.0f);
        int r1 = (int)(bx[2] / 32.0f);
        int c1 = (int)(bx[3] / 32.0f);
        int sr = r1 - r0, sc = c1 - c0;
        srs[t] = r0 + (t * sr) / PPOOL;
        sre[t] = r0 + ((t + 1) * sr + PPOOL - 1) / PPOOL;
        scs[t] = c0 + (t * sc) / PPOOL;
        sce[t] = c0 + ((t + 1) * sc + PPOOL - 1) / PPOOL;
    }
    __syncthreads();
    if (t < NP) {
        int ph = t / PPOOL, pw = t - ph * PPOOL;
        sinv[t] = 1.0f / (float)((sre[ph] - srs[ph]) * (sce[pw] - scs[pw]));
    }
    __syncthreads();
    if (t < NO) {
        float acc = bias[t];
        const float* Hb = H + (size_t)b * NP * IRC * OP + t;
        for (int p = 0; p < NP; ++p) {
            int ph = p / PPOOL, pw = p - ph * PPOOL;
            const float* Hp = Hb + (size_t)p * IRC * OP;
            int re = sre[ph], rs = srs[ph], ce = sce[pw], cs = scs[pw];
            float v = Hp[(size_t)(re * IW + ce) * OP] - Hp[(size_t)(rs * IW + ce) * OP]
                    - Hp[(size_t)(re * IW + cs) * OP] + Hp[(size_t)(rs * IW + cs) * OP];
            acc += v * sinv[p];
        }
        sl[t] = acc;
        if (t >= 80)
            out[(size_t)(4 * BATCH * NBOX) + ((size_t)b * NBOX + n) * (NCLS + 1) + (t - 80)] = acc;
    }
    __syncthreads();
    if (t == 0) {
        float best = sl[80]; int mi = 0;
        for (int s = 1; s <= NCLS; ++s) {
            float v = sl[80 + s];
            if (v > best) { best = v; mi = s; }
        }
        smi = mi;
    }
    __syncthreads();
    if (t < 4) out[((size_t)b * NBOX + n) * 4 + t] = sl[smi + t];
}

extern "C" void kernel_launch(void* const* d_in, const int* in_sizes, int n_in,
                              void* d_out, int out_size, void* d_ws, size_t ws_size,
                              hipStream_t stream) {
    const float* fm    = (const float*)d_in[0];
    const float* boxes = (const float*)d_in[1];
    const float* fcw   = (const float*)d_in[2];
    const float* fcb   = (const float*)d_in[3];
    const float* lw    = (const float*)d_in[4];
    const float* lb    = (const float*)d_in[5];
    const float* sw    = (const float*)d_in[6];
    const float* sb    = (const float*)d_in[7];
    float* out = (float*)d_out;

    float* ws   = (float*)d_ws;
    float* I    = ws;                               // 692,224 f
    float* Lt   = I + (size_t)BATCH * CH * IRC;     // 425,984 f
    float* bias = Lt + (size_t)FDIM * OP;           // 128 f (padded)
    float* Wc   = bias + 128;                       // 2,609,152 f
    float* H    = Wc + (size_t)KDIM * OP;           // 6,889,792 f
    float* Wpart = H;                               // aliased: Wpart dead before H written
    // Wpart needs 4*2,609,152 = 10,436,608 f; region after Wc is sized for max.
    // Total ws: ~57 MB.

    hipLaunchKernelGGL(k_lt, dim3((OP * FDIM + 255) / 256), dim3(256), 0, stream, lw, sw, Lt);
    hipLaunchKernelGGL(k_integral, dim3(256), dim3(256), 0, stream, fm, I);
    hipLaunchKernelGGL(k_bias, dim3(OP), dim3(256), 0, stream, lw, sw, fcb, lb, sb, bias);
    hipLaunchKernelGGL(k_wc, dim3(2, KDIM / 256, FSPLIT), dim3(256), 0, stream, fcw, Lt, Wpart);
    hipLaunchKernelGGL(k_reduce, dim3(KDIM * OP / 256), dim3(256), 0, stream, Wpart, Wc);
    hipLaunchKernelGGL(k_h, dim3((IRC + 255) / 256, NP, BATCH * 2), dim3(256), 0, stream, I, Wc, H);
    hipLaunchKernelGGL(k_out, dim3(NBOX, BATCH), dim3(128), 0, stream, boxes, H, bias, out);
}

// Round 3
// 409.068 us; speedup vs baseline: 2.3139x; 2.3139x over previous
//
#include <hip/hip_runtime.h>

#define BATCH 2
#define NBOX 500
#define CH 512
#define HFD 25
#define IW 26
#define IRC 676            // 26*26
#define IRCP 680           // padded channel stride
#define PPOOL 7
#define NP 49
#define NCLS 20
#define NO 101             // 80 loc + 21 score
#define OP2 112            // o padded to 7*16
#define MFRAG 7
#define KD 25088
#define FDIM 4096
#define NSTEP_TOT 128      // FDIM/32
#define S_WC ((size_t)KD * OP2)   // 2,809,856

typedef __attribute__((ext_vector_type(4))) float f32x4;
typedef __attribute__((ext_vector_type(8))) short bf16x8;
typedef __attribute__((ext_vector_type(4))) unsigned int u32v4;

#define MFMA16 __builtin_amdgcn_mfma_f32_16x16x32_bf16

// Exact 3-way truncation split of an fp32 pair into packed bf16 words.
// fp32 mantissa (24b) = 8+8+8 -> v == hi + mid + lo exactly (each a bf16 value).
#define SPLIT3PK(V0, V1, HW, MW, LW)                                   \
  {                                                                    \
    unsigned u0_ = __float_as_uint(V0), u1_ = __float_as_uint(V1);     \
    HW = (u0_ >> 16) | (u1_ & 0xffff0000u);                            \
    float r0_ = (V0) - __uint_as_float(u0_ & 0xffff0000u);             \
    float r1_ = (V1) - __uint_as_float(u1_ & 0xffff0000u);             \
    unsigned m0_ = __float_as_uint(r0_), m1_ = __float_as_uint(r1_);   \
    MW = (m0_ >> 16) | (m1_ & 0xffff0000u);                            \
    float s0_ = r0_ - __uint_as_float(m0_ & 0xffff0000u);              \
    float s1_ = r1_ - __uint_as_float(m1_ & 0xffff0000u);              \
    LW = (__float_as_uint(s0_) >> 16) |                                \
         (__float_as_uint(s1_) & 0xffff0000u);                         \
  }

// ---------------- A-tables: L=[l_w;s_w] -> MFMA A-frags, 3-way bf16 split --
// Ahi[(mf*128 + s)*64 + lane] = 8 bf16 = A[o=mf*16+(l&15)][f=s*32+(l>>4)*8+j]
__global__ void k_lt(const float* __restrict__ lw, const float* __restrict__ sw,
                     u32v4* __restrict__ Ahi, u32v4* __restrict__ Amd,
                     u32v4* __restrict__ Alo) {
    int t = blockIdx.x * 256 + threadIdx.x;
    if (t >= MFRAG * NSTEP_TOT * 64) return;
    int lane = t & 63;
    int wv = t >> 6;                 // (mf*128 + s)
    int s = wv & 127, mf = wv >> 7;
    int o = mf * 16 + (lane & 15);
    int f0 = s * 32 + (lane >> 4) * 8;
    float v[8];
    const float* row = nullptr;
    if (o < 80) row = lw + (size_t)o * FDIM;
    else if (o < NO) row = sw + (size_t)(o - 80) * FDIM;
    #pragma unroll
    for (int j = 0; j < 8; ++j) v[j] = row ? row[f0 + j] : 0.f;
    u32v4 hw, mw, lww;
    #pragma unroll
    for (int w = 0; w < 4; ++w)
        SPLIT3PK(v[2 * w], v[2 * w + 1], hw[w], mw[w], lww[w]);
    Ahi[(size_t)wv * 64 + lane] = hw;
    Amd[(size_t)wv * 64 + lane] = mw;
    Alo[(size_t)wv * 64 + lane] = lww;
}

// ---------------- integral image, c-major, padded stride 680 ---------------
__global__ void k_integral(const float* __restrict__ fm, float* __restrict__ I) {
    int gtid = blockIdx.x * blockDim.x + threadIdx.x;
    int wid = gtid >> 6;
    int lane = gtid & 63;
    if (wid >= BATCH * CH) return;
    const float* src = fm + (size_t)wid * (HFD * HFD);
    float* dst = I + (size_t)wid * IRCP;
    if (lane < IW) dst[lane] = 0.f;
    if (lane >= 1 && lane < IW) dst[lane * IW] = 0.f;
    int c = lane;
    float acc = 0.f;
    for (int r = 0; r < HFD; ++r) {
        float v = (c < HFD) ? src[r * HFD + c] : 0.f;
        #pragma unroll
        for (int d = 1; d < 32; d <<= 1) {
            float t = __shfl_up(v, d, 64);
            if (lane >= d) v += t;
        }
        acc += v;
        if (c < HFD) dst[(r + 1) * IW + (c + 1)] = acc;
    }
}

// ---------------- bias'[o] = L[o]·fc_b + {l_b|s_b}[o] ----------------------
__global__ void k_bias(const float* __restrict__ lw, const float* __restrict__ sw,
                       const float* __restrict__ fcb, const float* __restrict__ lb,
                       const float* __restrict__ sb, float* __restrict__ bias) {
    int o = blockIdx.x;
    __shared__ float red[256];
    float s = 0.f;
    if (o < NO) {
        const float* row = (o < 80) ? (lw + (size_t)o * FDIM) : (sw + (size_t)(o - 80) * FDIM);
        for (int f = threadIdx.x; f < FDIM; f += 256) s += row[f] * fcb[f];
    }
    red[threadIdx.x] = s;
    __syncthreads();
    for (int st = 128; st > 0; st >>= 1) {
        if ((int)threadIdx.x < st) red[threadIdx.x] += red[threadIdx.x + st];
        __syncthreads();
    }
    if (threadIdx.x == 0) {
        float bv = 0.f;
        if (o < 80) bv = red[0] + lb[o];
        else if (o < NO) bv = red[0] + sb[o - 80];
        bias[o] = bv;
    }
}

// ---------------- Wc partials via MFMA, 6-product exact-split scheme -------
// Wcp[fs][k][o] = sum_{f in chunk fs} L[o][f] * W1[f][k]
// grid (196, 4): x = k-block (128 k), y = f-chunk. 4 waves, wave = 32 k.
#define WC_STEP(CUR, NXT, S)                                                  \
  {                                                                           \
    u32v4 ah[MFRAG], am[MFRAG], al[MFRAG];                                    \
    _Pragma("unroll")                                                         \
    for (int mf = 0; mf < MFRAG; ++mf) {                                      \
      size_t ai = (size_t)((mf * 128 + fs * 32 + (S)) * 64 + lane);           \
      ah[mf] = Ahi[ai]; am[mf] = Amd[ai]; al[mf] = Alo[ai];                   \
    }                                                                         \
    if ((S) + 1 < 32) {                                                       \
      const float* bpn = bp + (size_t)((S) + 1) * 32 * KD;                    \
      _Pragma("unroll")                                                       \
      for (int nf = 0; nf < 2; ++nf)                                          \
        _Pragma("unroll")                                                     \
        for (int j = 0; j < 8; ++j)                                           \
          NXT[nf][j] = bpn[(size_t)j * KD + nf * 16];                         \
    }                                                                         \
    _Pragma("unroll")                                                         \
    for (int nf = 0; nf < 2; ++nf) {                                          \
      u32v4 bhw, bmw, blw;                                                    \
      _Pragma("unroll")                                                       \
      for (int w_ = 0; w_ < 4; ++w_)                                          \
        SPLIT3PK(CUR[nf][2 * w_], CUR[nf][2 * w_ + 1],                        \
                 bhw[w_], bmw[w_], blw[w_]);                                  \
      bf16x8 bh = __builtin_bit_cast(bf16x8, bhw);                            \
      bf16x8 bm = __builtin_bit_cast(bf16x8, bmw);                            \
      bf16x8 bl = __builtin_bit_cast(bf16x8, blw);                            \
      _Pragma("unroll")                                                       \
      for (int mf = 0; mf < MFRAG; ++mf) {                                    \
        bf16x8 a_h = __builtin_bit_cast(bf16x8, ah[mf]);                      \
        bf16x8 a_m = __builtin_bit_cast(bf16x8, am[mf]);                      \
        bf16x8 a_l = __builtin_bit_cast(bf16x8, al[mf]);                      \
        acc[mf][nf] = MFMA16(a_h, bh, acc[mf][nf], 0, 0, 0);                  \
        acc[mf][nf] = MFMA16(a_m, bh, acc[mf][nf], 0, 0, 0);                  \
        acc[mf][nf] = MFMA16(a_h, bm, acc[mf][nf], 0, 0, 0);                  \
        acc[mf][nf] = MFMA16(a_m, bm, acc[mf][nf], 0, 0, 0);                  \
        acc[mf][nf] = MFMA16(a_l, bh, acc[mf][nf], 0, 0, 0);                  \
        acc[mf][nf] = MFMA16(a_h, bl, acc[mf][nf], 0, 0, 0);                  \
      }                                                                       \
    }                                                                         \
  }

__global__ void __launch_bounds__(256, 1) k_wc(const float* __restrict__ W1,
                                               const u32v4* __restrict__ Ahi,
                                               const u32v4* __restrict__ Amd,
                                               const u32v4* __restrict__ Alo,
                                               float* __restrict__ Wcp) {
    int lane = threadIdx.x & 63;
    int w = threadIdx.x >> 6;        // wave 0..3
    int kb = blockIdx.x;             // 0..195
    int fs = blockIdx.y;             // 0..3
    int k0 = kb * 128 + w * 32;
    int row0 = (lane >> 4) * 8;
    int col = lane & 15;
    const float* bp = W1 + (size_t)(fs * 1024 + row0) * KD + k0 + col;

    f32x4 acc[MFRAG][2];
    #pragma unroll
    for (int mf = 0; mf < MFRAG; ++mf) {
        acc[mf][0] = (f32x4){0.f, 0.f, 0.f, 0.f};
        acc[mf][1] = (f32x4){0.f, 0.f, 0.f, 0.f};
    }
    float b0[2][8], b1[2][8];
    #pragma unroll
    for (int nf = 0; nf < 2; ++nf)
        #pragma unroll
        for (int j = 0; j < 8; ++j) b0[nf][j] = bp[(size_t)j * KD + nf * 16];

    for (int s = 0; s < 32; s += 2) {
        WC_STEP(b0, b1, s);
        WC_STEP(b1, b0, s + 1);
    }

    float* wp = Wcp + (size_t)fs * S_WC;
    #pragma unroll
    for (int mf = 0; mf < MFRAG; ++mf)
        #pragma unroll
        for (int nf = 0; nf < 2; ++nf) {
            size_t k = (size_t)k0 + nf * 16 + col;
            int o = mf * 16 + ((lane >> 4) << 2);
            *(f32x4*)(wp + k * OP2 + o) = acc[mf][nf];
        }
}

// ---------------- reduce f-chunks in place: Wcp[0] += Wcp[1..3] ------------
__global__ void k_red(float* __restrict__ Wcp) {
    size_t e = (size_t)blockIdx.x * 256 + threadIdx.x;
    Wcp[e] = Wcp[e] + Wcp[e + S_WC] + Wcp[e + 2 * S_WC] + Wcp[e + 3 * S_WC];
}

// ---------------- H[b][p][rc][o] = sum_c Wc[c*49+p][o] * I[b][c][rc] -------
// fp32 (corner-difference cancellation downstream forbids bf16 here).
// grid (6 rc-chunks of 128, 49 p, 2 b); 256 thr = 16 og x 16 rcg; tile 8o x 8rc.
__global__ void __launch_bounds__(256, 2) k_h(const float* __restrict__ I,
                                              const float* __restrict__ Wc,
                                              float* __restrict__ H) {
    int rc0 = blockIdx.x * 128;
    int p = blockIdx.y, b = blockIdx.z;
    int t = threadIdx.x;
    int og = t & 15, rcg = t >> 4;
    __shared__ float Ws[16][128];   // cols 112..127 are zero pad (in-bounds)
    __shared__ float Is[16][128];
    f32x4 acc[8][2];
    #pragma unroll
    for (int i = 0; i < 8; ++i) {
        acc[i][0] = (f32x4){0.f, 0.f, 0.f, 0.f};
        acc[i][1] = (f32x4){0.f, 0.f, 0.f, 0.f};
    }
    for (int c0 = 0; c0 < CH; c0 += 16) {
        __syncthreads();
        #pragma unroll
        for (int i = 0; i < 2; ++i) {
            int idx = t + i * 256;
            int row = idx >> 5, ln = idx & 31;
            f32x4 v = (f32x4){0.f, 0.f, 0.f, 0.f};
            if (ln < 28)
                v = *(const f32x4*)(Wc + ((size_t)(c0 + row) * NP + p) * OP2 + ln * 4);
            *(f32x4*)&Ws[row][ln * 4] = v;
            int rc = rc0 + ln * 4;
            f32x4 u = (f32x4){0.f, 0.f, 0.f, 0.f};
            if (rc < IRC)
                u = *(const f32x4*)(I + ((size_t)b * CH + c0 + row) * IRCP + rc);
            *(f32x4*)&Is[row][ln * 4] = u;
        }
        __syncthreads();
        #pragma unroll
        for (int c = 0; c < 16; ++c) {
            f32x4 w0 = *(const f32x4*)&Ws[c][og * 8];
            f32x4 w1 = *(const f32x4*)&Ws[c][og * 8 + 4];
            f32x4 i0 = *(const f32x4*)&Is[c][rcg * 8];
            f32x4 i1 = *(const f32x4*)&Is[c][rcg * 8 + 4];
            #pragma unroll
            for (int i = 0; i < 8; ++i) {
                float iv = (i < 4) ? i0[i] : i1[i - 4];
                acc[i][0] += w0 * iv;
                acc[i][1] += w1 * iv;
            }
        }
    }
    if (og < 14) {
        #pragma unroll
        for (int i = 0; i < 8; ++i) {
            int rc = rc0 + rcg * 8 + i;
            if (rc < IRC) {
                float* hp = H + (((size_t)(b * NP + p)) * IRC + rc) * OP2 + og * 8;
                *(f32x4*)hp = acc[i][0];
                *(f32x4*)(hp + 4) = acc[i][1];
            }
        }
    }
}

// ---------------- per-box gather + bias + argmax + outputs -----------------
__global__ void __launch_bounds__(128) k_out(const float* __restrict__ boxes,
                                             const float* __restrict__ H,
                                             const float* __restrict__ bias,
                                             float* __restrict__ out) {
    int n = blockIdx.x, b = blockIdx.y;
    int t = threadIdx.x;
    __shared__ int srs[PPOOL], sre[PPOOL], scs[PPOOL], sce[PPOOL];
    __shared__ float sinv[NP];
    __shared__ float sl[NO];
    __shared__ int smi;
    const float* bx = boxes + ((size_t)b * NBOX + n) * 4;
    if (t < PPOOL) {
        int r0 = (int)(bx[0] / 32.0f);
        int c0 = (int)(bx[1] / 32.0f);
        int r1 = (int)(bx[2] / 32.0f);
        int c1 = (int)(bx[3] / 32.0f);
        int sr = r1 - r0, sc = c1 - c0;
        srs[t] = r0 + (t * sr) / PPOOL;
        sre[t] = r0 + ((t + 1) * sr + PPOOL - 1) / PPOOL;
        scs[t] = c0 + (t * sc) / PPOOL;
        sce[t] = c0 + ((t + 1) * sc + PPOOL - 1) / PPOOL;
    }
    __syncthreads();
    if (t < NP) {
        int ph = t / PPOOL, pw = t - ph * PPOOL;
        sinv[t] = 1.0f / (float)((sre[ph] - srs[ph]) * (sce[pw] - scs[pw]));
    }
    __syncthreads();
    if (t < NO) {
        float acc = bias[t];
        const float* Hb = H + (size_t)b * NP * IRC * OP2 + t;
        for (int p = 0; p < NP; ++p) {
            int ph = p / PPOOL, pw = p - ph * PPOOL;
            const float* Hp = Hb + (size_t)p * IRC * OP2;
            int re = sre[ph], rs = srs[ph], ce = sce[pw], cs = scs[pw];
            float v = Hp[(size_t)(re * IW + ce) * OP2] - Hp[(size_t)(rs * IW + ce) * OP2]
                    - Hp[(size_t)(re * IW + cs) * OP2] + Hp[(size_t)(rs * IW + cs) * OP2];
            acc += v * sinv[p];
        }
        sl[t] = acc;
        if (t >= 80)
            out[(size_t)(4 * BATCH * NBOX) + ((size_t)b * NBOX + n) * (NCLS + 1) + (t - 80)] = acc;
    }
    __syncthreads();
    if (t == 0) {
        float best = sl[80]; int mi = 0;
        for (int s = 1; s <= NCLS; ++s) {
            float v = sl[80 + s];
            if (v > best) { best = v; mi = s; }
        }
        smi = mi;
    }
    __syncthreads();
    if (t < 4) out[((size_t)b * NBOX + n) * 4 + t] = sl[smi + t];
}

extern "C" void kernel_launch(void* const* d_in, const int* in_sizes, int n_in,
                              void* d_out, int out_size, void* d_ws, size_t ws_size,
                              hipStream_t stream) {
    const float* fm    = (const float*)d_in[0];
    const float* boxes = (const float*)d_in[1];
    const float* fcw   = (const float*)d_in[2];
    const float* fcb   = (const float*)d_in[3];
    const float* lw    = (const float*)d_in[4];
    const float* lb    = (const float*)d_in[5];
    const float* sw    = (const float*)d_in[6];
    const float* sb    = (const float*)d_in[7];
    float* out = (float*)d_out;

    float* ws = (float*)d_ws;
    float* I    = ws;                                        // 696,320 f
    u32v4* Ahi  = (u32v4*)(I + (size_t)BATCH * CH * IRCP);   // 57,344 * 16B
    u32v4* Amd  = Ahi + MFRAG * NSTEP_TOT * 64;
    u32v4* Alo  = Amd + MFRAG * NSTEP_TOT * 64;
    float* bias = (float*)(Alo + MFRAG * NSTEP_TOT * 64);    // 128 f
    float* Wcp  = bias + 128;                                // 4 * S_WC f (45 MB)
    float* Wc   = Wcp;                                       // after k_red
    float* H    = Wcp + S_WC;                                // 7.42M f <= 3*S_WC
    // total ws ~= 50.6 MB

    hipLaunchKernelGGL(k_lt, dim3(224), dim3(256), 0, stream, lw, sw, Ahi, Amd, Alo);
    hipLaunchKernelGGL(k_integral, dim3(256), dim3(256), 0, stream, fm, I);
    hipLaunchKernelGGL(k_bias, dim3(104), dim3(256), 0, stream, lw, sw, fcb, lb, sb, bias);
    hipLaunchKernelGGL(k_wc, dim3(196, 4), dim3(256), 0, stream, fcw, Ahi, Amd, Alo, Wcp);
    hipLaunchKernelGGL(k_red, dim3((unsigned)(S_WC / 256)), dim3(256), 0, stream, Wcp);
    hipLaunchKernelGGL(k_h, dim3(6, 49, 2), dim3(256), 0, stream, I, Wc, H);
    hipLaunchKernelGGL(k_out, dim3(NBOX, BATCH), dim3(128), 0, stream, boxes, H, bias, out);
}

// Round 4
// 293.087 us; speedup vs baseline: 3.2296x; 1.3957x over previous
//
#include <hip/hip_runtime.h>

#define BATCH 2
#define NBOX 500
#define CH 512
#define HFD 25
#define IW 26
#define IRC 676            // 26*26
#define IRCP2 768          // padded channel stride (covers rc-tile overreach)
#define PPOOL 7
#define NP 49
#define NCLS 20
#define NO 101             // 80 loc + 21 score
#define OP2 112            // o padded to 7*16
#define MFRAG 7
#define KD 25088
#define FDIM 4096
#define NSTEP_TOT 128      // FDIM/32
#define FSPLIT 8
#define WCSTEPS 16         // steps per f-chunk = 512/32
#define S_WC ((size_t)KD * OP2)   // 2,809,856
#define NFRAG_H (NP * 16 * MFRAG) // 5488 fragments per table for k_h

typedef __attribute__((ext_vector_type(4))) float f32x4;
typedef __attribute__((ext_vector_type(8))) short bf16x8;
typedef __attribute__((ext_vector_type(4))) unsigned int u32v4;

#define MFMA16 __builtin_amdgcn_mfma_f32_16x16x32_bf16

// ---- 2-way split of an fp32 pair: hi = trunc-bf16(v), mid = RN-bf16(v-hi).
// v = hi + mid + rho, |rho| <= 2^-17 |v|.
#define SPLIT2PK(V0, V1, HW, MW)                                       \
  {                                                                    \
    unsigned u0_ = __float_as_uint(V0), u1_ = __float_as_uint(V1);     \
    HW = (u0_ >> 16) | (u1_ & 0xffff0000u);                            \
    float r0_ = (V0) - __uint_as_float(u0_ & 0xffff0000u);             \
    float r1_ = (V1) - __uint_as_float(u1_ & 0xffff0000u);             \
    unsigned m0_ = __float_as_uint(r0_), m1_ = __float_as_uint(r1_);   \
    m0_ += 0x7fffu + ((m0_ >> 16) & 1u);                               \
    m1_ += 0x7fffu + ((m1_ >> 16) & 1u);                               \
    MW = (m0_ >> 16) | (m1_ & 0xffff0000u);                            \
  }

// ---- exact 3-way truncation split (24-bit mantissa = 8+8+8) ----
#define SPLIT3PK(V0, V1, HW, MW, LW)                                   \
  {                                                                    \
    unsigned u0_ = __float_as_uint(V0), u1_ = __float_as_uint(V1);     \
    HW = (u0_ >> 16) | (u1_ & 0xffff0000u);                            \
    float r0_ = (V0) - __uint_as_float(u0_ & 0xffff0000u);             \
    float r1_ = (V1) - __uint_as_float(u1_ & 0xffff0000u);             \
    unsigned m0_ = __float_as_uint(r0_), m1_ = __float_as_uint(r1_);   \
    MW = (m0_ >> 16) | (m1_ & 0xffff0000u);                            \
    float s0_ = r0_ - __uint_as_float(m0_ & 0xffff0000u);              \
    float s1_ = r1_ - __uint_as_float(m1_ & 0xffff0000u);              \
    LW = (__float_as_uint(s0_) >> 16) |                                \
         (__float_as_uint(s1_) & 0xffff0000u);                         \
  }

// ---------------- A-tables: L=[l_w;s_w] -> MFMA A-frags, 2-way split -------
// Ahi[(mf*128 + s)*64 + lane] = 8 bf16 = A[o=mf*16+(l&15)][f=s*32+(l>>4)*8+j]
__global__ void k_lt(const float* __restrict__ lw, const float* __restrict__ sw,
                     u32v4* __restrict__ Ahi, u32v4* __restrict__ Amd) {
    int t = blockIdx.x * 256 + threadIdx.x;
    if (t >= MFRAG * NSTEP_TOT * 64) return;
    int lane = t & 63;
    int wv = t >> 6;                 // (mf*128 + s)
    int s = wv & 127, mf = wv >> 7;
    int o = mf * 16 + (lane & 15);
    int f0 = s * 32 + (lane >> 4) * 8;
    float v[8];
    const float* row = nullptr;
    if (o < 80) row = lw + (size_t)o * FDIM;
    else if (o < NO) row = sw + (size_t)(o - 80) * FDIM;
    #pragma unroll
    for (int j = 0; j < 8; ++j) v[j] = row ? row[f0 + j] : 0.f;
    u32v4 hw, mw;
    #pragma unroll
    for (int w = 0; w < 4; ++w)
        SPLIT2PK(v[2 * w], v[2 * w + 1], hw[w], mw[w]);
    Ahi[(size_t)wv * 64 + lane] = hw;
    Amd[(size_t)wv * 64 + lane] = mw;
}

// ---------------- integral image, c-major, padded stride 768 ---------------
__global__ void k_integral(const float* __restrict__ fm, float* __restrict__ I) {
    int gtid = blockIdx.x * blockDim.x + threadIdx.x;
    int wid = gtid >> 6;
    int lane = gtid & 63;
    if (wid >= BATCH * CH) return;
    const float* src = fm + (size_t)wid * (HFD * HFD);
    float* dst = I + (size_t)wid * IRCP2;
    if (lane < IW) dst[lane] = 0.f;
    if (lane >= 1 && lane < IW) dst[lane * IW] = 0.f;
    int c = lane;
    float acc = 0.f;
    for (int r = 0; r < HFD; ++r) {
        float v = (c < HFD) ? src[r * HFD + c] : 0.f;
        #pragma unroll
        for (int d = 1; d < 32; d <<= 1) {
            float t = __shfl_up(v, d, 64);
            if (lane >= d) v += t;
        }
        acc += v;
        if (c < HFD) dst[(r + 1) * IW + (c + 1)] = acc;
    }
}

// ---------------- bias'[o] = L[o]·fc_b + {l_b|s_b}[o] ----------------------
__global__ void k_bias(const float* __restrict__ lw, const float* __restrict__ sw,
                       const float* __restrict__ fcb, const float* __restrict__ lb,
                       const float* __restrict__ sb, float* __restrict__ bias) {
    int o = blockIdx.x;
    __shared__ float red[256];
    float s = 0.f;
    if (o < NO) {
        const float* row = (o < 80) ? (lw + (size_t)o * FDIM) : (sw + (size_t)(o - 80) * FDIM);
        for (int f = threadIdx.x; f < FDIM; f += 256) s += row[f] * fcb[f];
    }
    red[threadIdx.x] = s;
    __syncthreads();
    for (int st = 128; st > 0; st >>= 1) {
        if ((int)threadIdx.x < st) red[threadIdx.x] += red[threadIdx.x + st];
        __syncthreads();
    }
    if (threadIdx.x == 0) {
        float bv = 0.f;
        if (o < 80) bv = red[0] + lb[o];
        else if (o < NO) bv = red[0] + sb[o - 80];
        bias[o] = bv;
    }
}

// ---------------- Wc partials via MFMA, 4-product symmetric split ----------
// Wcp[fs][k][o] = sum_{f in chunk fs} L[o][f] * W1[f][k]
// grid (196, 8): x = k-block (128 k), y = f-chunk(512). 4 waves, wave = 32 k.
#define WC_STEP(CUR, NXT, S)                                                  \
  {                                                                           \
    u32v4 ah[MFRAG], am[MFRAG];                                               \
    _Pragma("unroll")                                                         \
    for (int mf = 0; mf < MFRAG; ++mf) {                                      \
      size_t ai = (size_t)((mf * 128 + fs * WCSTEPS + (S)) * 64 + lane);      \
      ah[mf] = Ahi[ai]; am[mf] = Amd[ai];                                     \
    }                                                                         \
    if ((S) + 1 < WCSTEPS) {                                                  \
      const float* bpn = bp + (size_t)((S) + 1) * 32 * KD;                    \
      _Pragma("unroll")                                                       \
      for (int nf = 0; nf < 2; ++nf)                                          \
        _Pragma("unroll")                                                     \
        for (int j = 0; j < 8; ++j)                                           \
          NXT[nf][j] = bpn[(size_t)j * KD + nf * 16];                         \
    }                                                                         \
    _Pragma("unroll")                                                         \
    for (int nf = 0; nf < 2; ++nf) {                                          \
      u32v4 bhw, bmw;                                                         \
      _Pragma("unroll")                                                       \
      for (int w_ = 0; w_ < 4; ++w_)                                          \
        SPLIT2PK(CUR[nf][2 * w_], CUR[nf][2 * w_ + 1], bhw[w_], bmw[w_]);     \
      bf16x8 bh = __builtin_bit_cast(bf16x8, bhw);                            \
      bf16x8 bm = __builtin_bit_cast(bf16x8, bmw);                            \
      _Pragma("unroll")                                                       \
      for (int mf = 0; mf < MFRAG; ++mf) {                                    \
        bf16x8 a_h = __builtin_bit_cast(bf16x8, ah[mf]);                      \
        bf16x8 a_m = __builtin_bit_cast(bf16x8, am[mf]);                      \
        acc[mf][nf] = MFMA16(a_h, bh, acc[mf][nf], 0, 0, 0);                  \
        acc[mf][nf] = MFMA16(a_m, bh, acc[mf][nf], 0, 0, 0);                  \
        acc[mf][nf] = MFMA16(a_h, bm, acc[mf][nf], 0, 0, 0);                  \
        acc[mf][nf] = MFMA16(a_m, bm, acc[mf][nf], 0, 0, 0);                  \
      }                                                                       \
    }                                                                         \
  }

__global__ void __launch_bounds__(256, 3) k_wc(const float* __restrict__ W1,
                                               const u32v4* __restrict__ Ahi,
                                               const u32v4* __restrict__ Amd,
                                               float* __restrict__ Wcp) {
    int lane = threadIdx.x & 63;
    int w = threadIdx.x >> 6;        // wave 0..3
    int kb = blockIdx.x;             // 0..195
    int fs = blockIdx.y;             // 0..7
    int k0 = kb * 128 + w * 32;
    int row0 = (lane >> 4) * 8;
    int col = lane & 15;
    const float* bp = W1 + (size_t)(fs * 512 + row0) * KD + k0 + col;

    f32x4 acc[MFRAG][2];
    #pragma unroll
    for (int mf = 0; mf < MFRAG; ++mf) {
        acc[mf][0] = (f32x4){0.f, 0.f, 0.f, 0.f};
        acc[mf][1] = (f32x4){0.f, 0.f, 0.f, 0.f};
    }
    float b0[2][8], b1[2][8];
    #pragma unroll
    for (int nf = 0; nf < 2; ++nf)
        #pragma unroll
        for (int j = 0; j < 8; ++j) b0[nf][j] = bp[(size_t)j * KD + nf * 16];

    for (int s = 0; s < WCSTEPS; s += 2) {
        WC_STEP(b0, b1, s);
        WC_STEP(b1, b0, s + 1);
    }

    float* wp = Wcp + (size_t)fs * S_WC;
    #pragma unroll
    for (int mf = 0; mf < MFRAG; ++mf)
        #pragma unroll
        for (int nf = 0; nf < 2; ++nf) {
            size_t k = (size_t)k0 + nf * 16 + col;
            int o = mf * 16 + ((lane >> 4) << 2);
            *(f32x4*)(wp + k * OP2 + o) = acc[mf][nf];
        }
}

// ---------------- reduce f-chunks in place: Wcp[0] += Wcp[1..7] ------------
__global__ void k_red(float* __restrict__ Wcp) {
    size_t e = (size_t)blockIdx.x * 256 + threadIdx.x;
    float s = Wcp[e];
    #pragma unroll
    for (int i = 1; i < FSPLIT; ++i) s += Wcp[e + (size_t)i * S_WC];
    Wcp[e] = s;
}

// ---------------- Wc -> MFMA A-frag tables, 3-way split (for k_h) ----------
// Whi[((p*16+cs)*7+mf)*64 + lane] = 8 bf16 = Wc[c=cs*32+(l>>4)*8+j][o=mf*16+(l&15)]
// where Wc row index = c*49 + p.
__global__ void k_wsplit(const float* __restrict__ Wc, u32v4* __restrict__ Whi,
                         u32v4* __restrict__ Wmd, u32v4* __restrict__ Wlo) {
    int t = blockIdx.x * 256 + threadIdx.x;   // over NFRAG_H*64
    int lane = t & 63;
    int fi = t >> 6;
    int p = fi / (16 * MFRAG);
    int rem = fi - p * (16 * MFRAG);
    int cs = rem / MFRAG, mf = rem - cs * MFRAG;
    int o = mf * 16 + (lane & 15);
    int c0 = cs * 32 + (lane >> 4) * 8;
    float v[8];
    #pragma unroll
    for (int j = 0; j < 8; ++j)
        v[j] = Wc[((size_t)(c0 + j) * NP + p) * OP2 + o];
    u32v4 hw, mw, lww;
    #pragma unroll
    for (int w = 0; w < 4; ++w)
        SPLIT3PK(v[2 * w], v[2 * w + 1], hw[w], mw[w], lww[w]);
    Whi[(size_t)fi * 64 + lane] = hw;
    Wmd[(size_t)fi * 64 + lane] = mw;
    Wlo[(size_t)fi * 64 + lane] = lww;
}

// ---------------- H[b][p][rc][o] = sum_c Wc[c*49+p][o] * I[b][c][rc] -------
// MFMA, 6-product (H feeds corner-difference cancellation -> need ~2^-24 rel).
// grid (6, 49, 2): x = rc-tile(128), y = p, z = b. Wave covers 32 rc (2 nf).
#define KH_STEP(CUR, NXT, S)                                                  \
  {                                                                           \
    if ((S) + 1 < 16) {                                                       \
      _Pragma("unroll")                                                       \
      for (int nf = 0; nf < 2; ++nf)                                          \
        _Pragma("unroll")                                                     \
        for (int j = 0; j < 8; ++j)                                           \
          NXT[nf][j] = Ib[(size_t)(((S) + 1) * 32 + rowg * 8 + j) * IRCP2 + nf * 16]; \
    }                                                                         \
    bf16x8 bh[2], bm[2], bl[2];                                               \
    _Pragma("unroll")                                                         \
    for (int nf = 0; nf < 2; ++nf) {                                          \
      u32v4 bhw, bmw, blw;                                                    \
      _Pragma("unroll")                                                       \
      for (int w_ = 0; w_ < 4; ++w_)                                          \
        SPLIT3PK(CUR[nf][2 * w_], CUR[nf][2 * w_ + 1], bhw[w_], bmw[w_], blw[w_]); \
      bh[nf] = __builtin_bit_cast(bf16x8, bhw);                               \
      bm[nf] = __builtin_bit_cast(bf16x8, bmw);                               \
      bl[nf] = __builtin_bit_cast(bf16x8, blw);                               \
    }                                                                         \
    _Pragma("unroll")                                                         \
    for (int mf = 0; mf < MFRAG; ++mf) {                                      \
      size_t ai = (size_t)(((p * 16 + (S)) * MFRAG + mf) * 64 + lane);        \
      bf16x8 a_h = __builtin_bit_cast(bf16x8, Whi[ai]);                       \
      bf16x8 a_m = __builtin_bit_cast(bf16x8, Wmd[ai]);                       \
      bf16x8 a_l = __builtin_bit_cast(bf16x8, Wlo[ai]);                       \
      _Pragma("unroll")                                                       \
      for (int nf = 0; nf < 2; ++nf) {                                        \
        acc[mf][nf] = MFMA16(a_h, bh[nf], acc[mf][nf], 0, 0, 0);              \
        acc[mf][nf] = MFMA16(a_m, bh[nf], acc[mf][nf], 0, 0, 0);              \
        acc[mf][nf] = MFMA16(a_h, bm[nf], acc[mf][nf], 0, 0, 0);              \
        acc[mf][nf] = MFMA16(a_m, bm[nf], acc[mf][nf], 0, 0, 0);              \
        acc[mf][nf] = MFMA16(a_l, bh[nf], acc[mf][nf], 0, 0, 0);              \
        acc[mf][nf] = MFMA16(a_h, bl[nf], acc[mf][nf], 0, 0, 0);              \
      }                                                                       \
    }                                                                         \
  }

__global__ void __launch_bounds__(256, 2) k_h(const float* __restrict__ I,
                                              const u32v4* __restrict__ Whi,
                                              const u32v4* __restrict__ Wmd,
                                              const u32v4* __restrict__ Wlo,
                                              float* __restrict__ H) {
    int lane = threadIdx.x & 63;
    int w = threadIdx.x >> 6;
    int rcb = blockIdx.x, p = blockIdx.y, b = blockIdx.z;
    int col = lane & 15, rowg = lane >> 4;
    int rcw = rcb * 128 + w * 32;                 // wave's rc base
    const float* Ib = I + (size_t)b * CH * IRCP2 + rcw + col;

    f32x4 acc[MFRAG][2];
    #pragma unroll
    for (int mf = 0; mf < MFRAG; ++mf) {
        acc[mf][0] = (f32x4){0.f, 0.f, 0.f, 0.f};
        acc[mf][1] = (f32x4){0.f, 0.f, 0.f, 0.f};
    }
    float ib0[2][8], ib1[2][8];
    #pragma unroll
    for (int nf = 0; nf < 2; ++nf)
        #pragma unroll
        for (int j = 0; j < 8; ++j)
            ib0[nf][j] = Ib[(size_t)(rowg * 8 + j) * IRCP2 + nf * 16];

    for (int s = 0; s < 16; s += 2) {
        KH_STEP(ib0, ib1, s);
        KH_STEP(ib1, ib0, s + 1);
    }

    #pragma unroll
    for (int mf = 0; mf < MFRAG; ++mf)
        #pragma unroll
        for (int nf = 0; nf < 2; ++nf) {
            int rc = rcw + nf * 16 + col;
            if (rc < IRC) {
                float* hp = H + (((size_t)(b * NP + p)) * IRC + rc) * OP2
                            + mf * 16 + rowg * 4;
                *(f32x4*)hp = acc[mf][nf];
            }
        }
}

// ---------------- per-box gather + bias + argmax + outputs -----------------
__global__ void __launch_bounds__(128) k_out(const float* __restrict__ boxes,
                                             const float* __restrict__ H,
                                             const float* __restrict__ bias,
                                             float* __restrict__ out) {
    int n = blockIdx.x, b = blockIdx.y;
    int t = threadIdx.x;
    __shared__ int srs[PPOOL], sre[PPOOL], scs[PPOOL], sce[PPOOL];
    __shared__ float sinv[NP];
    __shared__ float sl[NO];
    __shared__ int smi;
    const float* bx = boxes + ((size_t)b * NBOX + n) * 4;
    if (t < PPOOL) {
        int r0 = (int)(bx[0] / 32.0f);
        int c0 = (int)(bx[1] / 32.0f);
        int r1 = (int)(bx[2] / 32.0f);
        int c1 = (int)(bx[3] / 32.0f);
        int sr = r1 - r0, sc = c1 - c0;
        srs[t] = r0 + (t * sr) / PPOOL;
        sre[t] = r0 + ((t + 1) * sr + PPOOL - 1) / PPOOL;
        scs[t] = c0 + (t * sc) / PPOOL;
        sce[t] = c0 + ((t + 1) * sc + PPOOL - 1) / PPOOL;
    }
    __syncthreads();
    if (t < NP) {
        int ph = t / PPOOL, pw = t - ph * PPOOL;
        sinv[t] = 1.0f / (float)((sre[ph] - srs[ph]) * (sce[pw] - scs[pw]));
    }
    __syncthreads();
    if (t < NO) {
        float acc = bias[t];
        const float* Hb = H + (size_t)b * NP * IRC * OP2 + t;
        for (int p = 0; p < NP; ++p) {
            int ph = p / PPOOL, pw = p - ph * PPOOL;
            const float* Hp = Hb + (size_t)p * IRC * OP2;
            int re = sre[ph], rs = srs[ph], ce = sce[pw], cs = scs[pw];
            float v = Hp[(size_t)(re * IW + ce) * OP2] - Hp[(size_t)(rs * IW + ce) * OP2]
                    - Hp[(size_t)(re * IW + cs) * OP2] + Hp[(size_t)(rs * IW + cs) * OP2];
            acc += v * sinv[p];
        }
        sl[t] = acc;
        if (t >= 80)
            out[(size_t)(4 * BATCH * NBOX) + ((size_t)b * NBOX + n) * (NCLS + 1) + (t - 80)] = acc;
    }
    __syncthreads();
    if (t == 0) {
        float best = sl[80]; int mi = 0;
        for (int s = 1; s <= NCLS; ++s) {
            float v = sl[80 + s];
            if (v > best) { best = v; mi = s; }
        }
        smi = mi;
    }
    __syncthreads();
    if (t < 4) out[((size_t)b * NBOX + n) * 4 + t] = sl[smi + t];
}

extern "C" void kernel_launch(void* const* d_in, const int* in_sizes, int n_in,
                              void* d_out, int out_size, void* d_ws, size_t ws_size,
                              hipStream_t stream) {
    const float* fm    = (const float*)d_in[0];
    const float* boxes = (const float*)d_in[1];
    const float* fcw   = (const float*)d_in[2];
    const float* fcb   = (const float*)d_in[3];
    const float* lw    = (const float*)d_in[4];
    const float* lb    = (const float*)d_in[5];
    const float* sw    = (const float*)d_in[6];
    const float* sb    = (const float*)d_in[7];
    float* out = (float*)d_out;

    float* ws = (float*)d_ws;
    float* I    = ws;                                        // 2*512*768 = 786,432 f
    u32v4* Ahi  = (u32v4*)(I + (size_t)BATCH * CH * IRCP2);  // 57,344 frag-words
    u32v4* Amd  = Ahi + MFRAG * NSTEP_TOT * 64;
    float* bias = (float*)(Amd + MFRAG * NSTEP_TOT * 64);    // 128 f
    float* Wcp  = bias + 128;                                // 8 * S_WC f (90 MB)
    float* Wc   = Wcp;                                       // after k_red
    u32v4* Whi  = (u32v4*)(Wcp + (size_t)FSPLIT * S_WC);     // 351,232 each
    u32v4* Wmd  = Whi + (size_t)NFRAG_H * 64;
    u32v4* Wlo  = Wmd + (size_t)NFRAG_H * 64;
    float* H    = (float*)(Wlo + (size_t)NFRAG_H * 64);      // 7,419,392 f
    // total ws ~= 142 MB

    hipLaunchKernelGGL(k_lt, dim3(224), dim3(256), 0, stream, lw, sw, Ahi, Amd);
    hipLaunchKernelGGL(k_integral, dim3(256), dim3(256), 0, stream, fm, I);
    hipLaunchKernelGGL(k_bias, dim3(104), dim3(256), 0, stream, lw, sw, fcb, lb, sb, bias);
    hipLaunchKernelGGL(k_wc, dim3(196, FSPLIT), dim3(256), 0, stream, fcw, Ahi, Amd, Wcp);
    hipLaunchKernelGGL(k_red, dim3((unsigned)(S_WC / 256)), dim3(256), 0, stream, Wcp);
    hipLaunchKernelGGL(k_wsplit, dim3(NFRAG_H * 64 / 256), dim3(256), 0, stream, Wc, Whi, Wmd, Wlo);
    hipLaunchKernelGGL(k_h, dim3(6, NP, BATCH), dim3(256), 0, stream, I, Whi, Wmd, Wlo, H);
    hipLaunchKernelGGL(k_out, dim3(NBOX, BATCH), dim3(128), 0, stream, boxes, H, bias, out);
}

// Round 5
// 280.521 us; speedup vs baseline: 3.3742x; 1.0448x over previous
//
#include <hip/hip_runtime.h>

#define BATCH 2
#define NBOX 500
#define CH 512
#define HFD 25
#define IW 26
#define IRC 676            // 26*26
#define IRCP2 768          // padded channel stride (covers rc-tile overreach)
#define PPOOL 7
#define NP 49
#define NCLS 20
#define NO 101             // 80 loc + 21 score
#define OP2 112            // o padded to 7*16
#define MFRAG 7
#define KD 25088
#define FDIM 4096
#define NSTEP_TOT 128      // FDIM/32
#define FSPLIT 8
#define WCSTEPS 16         // steps per f-chunk = 512/32
#define S_WC ((size_t)KD * OP2)   // 2,809,856
#define NFRAG_H (NP * 16 * MFRAG) // 5488 fragments per table for k_h

typedef __attribute__((ext_vector_type(4))) float f32x4;
typedef __attribute__((ext_vector_type(8))) short bf16x8;
typedef __attribute__((ext_vector_type(4))) unsigned int u32v4;

#define MFMA16 __builtin_amdgcn_mfma_f32_16x16x32_bf16

// ---- 2-way split of an fp32 pair: hi = trunc-bf16(v), mid = RN-bf16(v-hi).
// v = hi + mid + rho, |rho| <= 2^-17 |v|.
#define SPLIT2PK(V0, V1, HW, MW)                                       \
  {                                                                    \
    unsigned u0_ = __float_as_uint(V0), u1_ = __float_as_uint(V1);     \
    HW = (u0_ >> 16) | (u1_ & 0xffff0000u);                            \
    float r0_ = (V0) - __uint_as_float(u0_ & 0xffff0000u);             \
    float r1_ = (V1) - __uint_as_float(u1_ & 0xffff0000u);             \
    unsigned m0_ = __float_as_uint(r0_), m1_ = __float_as_uint(r1_);   \
    m0_ += 0x7fffu + ((m0_ >> 16) & 1u);                               \
    m1_ += 0x7fffu + ((m1_ >> 16) & 1u);                               \
    MW = (m0_ >> 16) | (m1_ & 0xffff0000u);                            \
  }

// ---- exact 3-way truncation split (24-bit mantissa = 8+8+8) ----
#define SPLIT3PK(V0, V1, HW, MW, LW)                                   \
  {                                                                    \
    unsigned u0_ = __float_as_uint(V0), u1_ = __float_as_uint(V1);     \
    HW = (u0_ >> 16) | (u1_ & 0xffff0000u);                            \
    float r0_ = (V0) - __uint_as_float(u0_ & 0xffff0000u);             \
    float r1_ = (V1) - __uint_as_float(u1_ & 0xffff0000u);             \
    unsigned m0_ = __float_as_uint(r0_), m1_ = __float_as_uint(r1_);   \
    MW = (m0_ >> 16) | (m1_ & 0xffff0000u);                            \
    float s0_ = r0_ - __uint_as_float(m0_ & 0xffff0000u);              \
    float s1_ = r1_ - __uint_as_float(m1_ & 0xffff0000u);              \
    LW = (__float_as_uint(s0_) >> 16) |                                \
         (__float_as_uint(s1_) & 0xffff0000u);                         \
  }

// ---------------- A-tables: L=[l_w;s_w] -> MFMA A-frags, 2-way split -------
// Ahi[(mf*128 + s)*64 + lane] = 8 bf16 = A[o=mf*16+(l&15)][f=s*32+(l>>4)*8+j]
__global__ void k_lt(const float* __restrict__ lw, const float* __restrict__ sw,
                     u32v4* __restrict__ Ahi, u32v4* __restrict__ Amd) {
    int t = blockIdx.x * 256 + threadIdx.x;
    if (t >= MFRAG * NSTEP_TOT * 64) return;
    int lane = t & 63;
    int wv = t >> 6;                 // (mf*128 + s)
    int s = wv & 127, mf = wv >> 7;
    int o = mf * 16 + (lane & 15);
    int f0 = s * 32 + (lane >> 4) * 8;
    float v[8];
    const float* row = nullptr;
    if (o < 80) row = lw + (size_t)o * FDIM;
    else if (o < NO) row = sw + (size_t)(o - 80) * FDIM;
    #pragma unroll
    for (int j = 0; j < 8; ++j) v[j] = row ? row[f0 + j] : 0.f;
    u32v4 hw, mw;
    #pragma unroll
    for (int w = 0; w < 4; ++w)
        SPLIT2PK(v[2 * w], v[2 * w + 1], hw[w], mw[w]);
    Ahi[(size_t)wv * 64 + lane] = hw;
    Amd[(size_t)wv * 64 + lane] = mw;
}

// ---------------- integral image, c-major, padded stride 768 ---------------
__global__ void k_integral(const float* __restrict__ fm, float* __restrict__ I) {
    int gtid = blockIdx.x * blockDim.x + threadIdx.x;
    int wid = gtid >> 6;
    int lane = gtid & 63;
    if (wid >= BATCH * CH) return;
    const float* src = fm + (size_t)wid * (HFD * HFD);
    float* dst = I + (size_t)wid * IRCP2;
    if (lane < IW) dst[lane] = 0.f;
    if (lane >= 1 && lane < IW) dst[lane * IW] = 0.f;
    int c = lane;
    float acc = 0.f;
    for (int r = 0; r < HFD; ++r) {
        float v = (c < HFD) ? src[r * HFD + c] : 0.f;
        #pragma unroll
        for (int d = 1; d < 32; d <<= 1) {
            float t = __shfl_up(v, d, 64);
            if (lane >= d) v += t;
        }
        acc += v;
        if (c < HFD) dst[(r + 1) * IW + (c + 1)] = acc;
    }
}

// ---------------- bias'[o] = L[o]·fc_b + {l_b|s_b}[o] ----------------------
__global__ void k_bias(const float* __restrict__ lw, const float* __restrict__ sw,
                       const float* __restrict__ fcb, const float* __restrict__ lb,
                       const float* __restrict__ sb, float* __restrict__ bias) {
    int o = blockIdx.x;
    __shared__ float red[256];
    float s = 0.f;
    if (o < NO) {
        const float* row = (o < 80) ? (lw + (size_t)o * FDIM) : (sw + (size_t)(o - 80) * FDIM);
        for (int f = threadIdx.x; f < FDIM; f += 256) s += row[f] * fcb[f];
    }
    red[threadIdx.x] = s;
    __syncthreads();
    for (int st = 128; st > 0; st >>= 1) {
        if ((int)threadIdx.x < st) red[threadIdx.x] += red[threadIdx.x + st];
        __syncthreads();
    }
    if (threadIdx.x == 0) {
        float bv = 0.f;
        if (o < 80) bv = red[0] + lb[o];
        else if (o < NO) bv = red[0] + sb[o - 80];
        bias[o] = bv;
    }
}

// ---------------- Wc partials via MFMA, 3-product split --------------------
// Wcp[fs][k][o] = sum_{f in chunk fs} L[o][f] * W1[f][k]
// grid (196, 8): x = k-block (128 k), y = f-chunk(512). 4 waves, wave = 32 k.
// products: ah*bh + am*bh + ah*bm  (dropped am*bm ~ 2^-18 rel)
#define WC_STEP(CUR, NXT, S)                                                  \
  {                                                                           \
    u32v4 ah[MFRAG], am[MFRAG];                                               \
    _Pragma("unroll")                                                         \
    for (int mf = 0; mf < MFRAG; ++mf) {                                      \
      size_t ai = (size_t)((mf * 128 + fs * WCSTEPS + (S)) * 64 + lane);      \
      ah[mf] = Ahi[ai]; am[mf] = Amd[ai];                                     \
    }                                                                         \
    if ((S) + 1 < WCSTEPS) {                                                  \
      const float* bpn = bp + (size_t)((S) + 1) * 32 * KD;                    \
      _Pragma("unroll")                                                       \
      for (int nf = 0; nf < 2; ++nf)                                          \
        _Pragma("unroll")                                                     \
        for (int j = 0; j < 8; ++j)                                           \
          NXT[nf][j] = bpn[(size_t)j * KD + nf * 16];                         \
    }                                                                         \
    _Pragma("unroll")                                                         \
    for (int nf = 0; nf < 2; ++nf) {                                          \
      u32v4 bhw, bmw;                                                         \
      _Pragma("unroll")                                                       \
      for (int w_ = 0; w_ < 4; ++w_)                                          \
        SPLIT2PK(CUR[nf][2 * w_], CUR[nf][2 * w_ + 1], bhw[w_], bmw[w_]);     \
      bf16x8 bh = __builtin_bit_cast(bf16x8, bhw);                            \
      bf16x8 bm = __builtin_bit_cast(bf16x8, bmw);                            \
      _Pragma("unroll")                                                       \
      for (int mf = 0; mf < MFRAG; ++mf) {                                    \
        bf16x8 a_h = __builtin_bit_cast(bf16x8, ah[mf]);                      \
        bf16x8 a_m = __builtin_bit_cast(bf16x8, am[mf]);                      \
        acc[mf][nf] = MFMA16(a_h, bh, acc[mf][nf], 0, 0, 0);                  \
        acc[mf][nf] = MFMA16(a_m, bh, acc[mf][nf], 0, 0, 0);                  \
        acc[mf][nf] = MFMA16(a_h, bm, acc[mf][nf], 0, 0, 0);                  \
      }                                                                       \
    }                                                                         \
  }

__global__ void __launch_bounds__(256, 3) k_wc(const float* __restrict__ W1,
                                               const u32v4* __restrict__ Ahi,
                                               const u32v4* __restrict__ Amd,
                                               float* __restrict__ Wcp) {
    int lane = threadIdx.x & 63;
    int w = threadIdx.x >> 6;        // wave 0..3
    int kb = blockIdx.x;             // 0..195
    int fs = blockIdx.y;             // 0..7
    int k0 = kb * 128 + w * 32;
    int row0 = (lane >> 4) * 8;
    int col = lane & 15;
    const float* bp = W1 + (size_t)(fs * 512 + row0) * KD + k0 + col;

    f32x4 acc[MFRAG][2];
    #pragma unroll
    for (int mf = 0; mf < MFRAG; ++mf) {
        acc[mf][0] = (f32x4){0.f, 0.f, 0.f, 0.f};
        acc[mf][1] = (f32x4){0.f, 0.f, 0.f, 0.f};
    }
    float b0[2][8], b1[2][8];
    #pragma unroll
    for (int nf = 0; nf < 2; ++nf)
        #pragma unroll
        for (int j = 0; j < 8; ++j) b0[nf][j] = bp[(size_t)j * KD + nf * 16];

    for (int s = 0; s < WCSTEPS; s += 2) {
        WC_STEP(b0, b1, s);
        WC_STEP(b1, b0, s + 1);
    }

    float* wp = Wcp + (size_t)fs * S_WC;
    #pragma unroll
    for (int mf = 0; mf < MFRAG; ++mf)
        #pragma unroll
        for (int nf = 0; nf < 2; ++nf) {
            size_t k = (size_t)k0 + nf * 16 + col;
            int o = mf * 16 + ((lane >> 4) << 2);
            *(f32x4*)(wp + k * OP2 + o) = acc[mf][nf];
        }
}

// ---------------- fused: reduce 8 f-chunks + 3-way split -> k_h A-tables ---
// Whi[((p*16+cs)*7+mf)*64 + lane] = 8 bf16 = Wc[c=cs*32+(l>>4)*8+j][o=mf*16+(l&15)]
// where Wc row index = c*49 + p and Wc = sum over FSPLIT partial slices.
__global__ void k_redsplit(const float* __restrict__ Wcp, u32v4* __restrict__ Whi,
                           u32v4* __restrict__ Wmd, u32v4* __restrict__ Wlo) {
    int t = blockIdx.x * 256 + threadIdx.x;   // over NFRAG_H*64
    int lane = t & 63;
    int fi = t >> 6;
    int p = fi / (16 * MFRAG);
    int rem = fi - p * (16 * MFRAG);
    int cs = rem / MFRAG, mf = rem - cs * MFRAG;
    int o = mf * 16 + (lane & 15);
    int c0 = cs * 32 + (lane >> 4) * 8;
    float v[8];
    #pragma unroll
    for (int j = 0; j < 8; ++j) {
        size_t base = ((size_t)(c0 + j) * NP + p) * OP2 + o;
        float s = 0.f;
        #pragma unroll
        for (int i = 0; i < FSPLIT; ++i) s += Wcp[base + (size_t)i * S_WC];
        v[j] = s;
    }
    u32v4 hw, mw, lww;
    #pragma unroll
    for (int w = 0; w < 4; ++w)
        SPLIT3PK(v[2 * w], v[2 * w + 1], hw[w], mw[w], lww[w]);
    Whi[(size_t)fi * 64 + lane] = hw;
    Wmd[(size_t)fi * 64 + lane] = mw;
    Wlo[(size_t)fi * 64 + lane] = lww;
}

// ---------------- H[b][p][rc][o] = sum_c Wc[c*49+p][o] * I[b][c][rc] -------
// MFMA, 6-product (H feeds corner-difference cancellation -> need ~2^-24 rel).
// grid (6, 49, 2): x = rc-tile(128), y = p, z = b. Wave covers 32 rc (2 nf).
#define KH_STEP(CUR, NXT, S)                                                  \
  {                                                                           \
    if ((S) + 1 < 16) {                                                       \
      _Pragma("unroll")                                                       \
      for (int nf = 0; nf < 2; ++nf)                                          \
        _Pragma("unroll")                                                     \
        for (int j = 0; j < 8; ++j)                                           \
          NXT[nf][j] = Ib[(size_t)(((S) + 1) * 32 + rowg * 8 + j) * IRCP2 + nf * 16]; \
    }                                                                         \
    bf16x8 bh[2], bm[2], bl[2];                                               \
    _Pragma("unroll")                                                         \
    for (int nf = 0; nf < 2; ++nf) {                                          \
      u32v4 bhw, bmw, blw;                                                    \
      _Pragma("unroll")                                                       \
      for (int w_ = 0; w_ < 4; ++w_)                                          \
        SPLIT3PK(CUR[nf][2 * w_], CUR[nf][2 * w_ + 1], bhw[w_], bmw[w_], blw[w_]); \
      bh[nf] = __builtin_bit_cast(bf16x8, bhw);                               \
      bm[nf] = __builtin_bit_cast(bf16x8, bmw);                               \
      bl[nf] = __builtin_bit_cast(bf16x8, blw);                               \
    }                                                                         \
    _Pragma("unroll")                                                         \
    for (int mf = 0; mf < MFRAG; ++mf) {                                      \
      size_t ai = (size_t)(((p * 16 + (S)) * MFRAG + mf) * 64 + lane);        \
      bf16x8 a_h = __builtin_bit_cast(bf16x8, Whi[ai]);                       \
      bf16x8 a_m = __builtin_bit_cast(bf16x8, Wmd[ai]);                       \
      bf16x8 a_l = __builtin_bit_cast(bf16x8, Wlo[ai]);                       \
      _Pragma("unroll")                                                       \
      for (int nf = 0; nf < 2; ++nf) {                                        \
        acc[mf][nf] = MFMA16(a_h, bh[nf], acc[mf][nf], 0, 0, 0);              \
        acc[mf][nf] = MFMA16(a_m, bh[nf], acc[mf][nf], 0, 0, 0);              \
        acc[mf][nf] = MFMA16(a_h, bm[nf], acc[mf][nf], 0, 0, 0);              \
        acc[mf][nf] = MFMA16(a_m, bm[nf], acc[mf][nf], 0, 0, 0);              \
        acc[mf][nf] = MFMA16(a_l, bh[nf], acc[mf][nf], 0, 0, 0);              \
        acc[mf][nf] = MFMA16(a_h, bl[nf], acc[mf][nf], 0, 0, 0);              \
      }                                                                       \
    }                                                                         \
  }

__global__ void __launch_bounds__(256, 2) k_h(const float* __restrict__ I,
                                              const u32v4* __restrict__ Whi,
                                              const u32v4* __restrict__ Wmd,
                                              const u32v4* __restrict__ Wlo,
                                              float* __restrict__ H) {
    int lane = threadIdx.x & 63;
    int w = threadIdx.x >> 6;
    int rcb = blockIdx.x, p = blockIdx.y, b = blockIdx.z;
    int col = lane & 15, rowg = lane >> 4;
    int rcw = rcb * 128 + w * 32;                 // wave's rc base
    const float* Ib = I + (size_t)b * CH * IRCP2 + rcw + col;

    f32x4 acc[MFRAG][2];
    #pragma unroll
    for (int mf = 0; mf < MFRAG; ++mf) {
        acc[mf][0] = (f32x4){0.f, 0.f, 0.f, 0.f};
        acc[mf][1] = (f32x4){0.f, 0.f, 0.f, 0.f};
    }
    float ib0[2][8], ib1[2][8];
    #pragma unroll
    for (int nf = 0; nf < 2; ++nf)
        #pragma unroll
        for (int j = 0; j < 8; ++j)
            ib0[nf][j] = Ib[(size_t)(rowg * 8 + j) * IRCP2 + nf * 16];

    for (int s = 0; s < 16; s += 2) {
        KH_STEP(ib0, ib1, s);
        KH_STEP(ib1, ib0, s + 1);
    }

    #pragma unroll
    for (int mf = 0; mf < MFRAG; ++mf)
        #pragma unroll
        for (int nf = 0; nf < 2; ++nf) {
            int rc = rcw + nf * 16 + col;
            if (rc < IRC) {
                float* hp = H + (((size_t)(b * NP + p)) * IRC + rc) * OP2
                            + mf * 16 + rowg * 4;
                *(f32x4*)hp = acc[mf][nf];
            }
        }
}

// ---------------- per-box gather + bias + argmax + outputs -----------------
// 256 threads: o = t&127 (o<101 active), p-half = t>>7 -> 2-way LDS reduce.
__global__ void __launch_bounds__(256) k_out(const float* __restrict__ boxes,
                                             const float* __restrict__ H,
                                             const float* __restrict__ bias,
                                             float* __restrict__ out) {
    int n = blockIdx.x, b = blockIdx.y;
    int t = threadIdx.x;
    __shared__ int srs[PPOOL], sre[PPOOL], scs[PPOOL], sce[PPOOL];
    __shared__ float sinv[NP];
    __shared__ float psum[2][NO];
    __shared__ float sl[NO];
    __shared__ int smi;
    const float* bx = boxes + ((size_t)b * NBOX + n) * 4;
    if (t < PPOOL) {
        int r0 = (int)(bx[0] / 32.0f);
        int c0 = (int)(bx[1] / 32.0f);
        int r1 = (int)(bx[2] / 32.0f);
        int c1 = (int)(bx[3] / 32.0f);
        int sr = r1 - r0, sc = c1 - c0;
        srs[t] = r0 + (t * sr) / PPOOL;
        sre[t] = r0 + ((t + 1) * sr + PPOOL - 1) / PPOOL;
        scs[t] = c0 + (t * sc) / PPOOL;
        sce[t] = c0 + ((t + 1) * sc + PPOOL - 1) / PPOOL;
    }
    __syncthreads();
    if (t < NP) {
        int ph = t / PPOOL, pw = t - ph * PPOOL;
        sinv[t] = 1.0f / (float)((sre[ph] - srs[ph]) * (sce[pw] - scs[pw]));
    }
    __syncthreads();
    int o = t & 127, half = t >> 7;
    if (o < NO) {
        int p0 = half * 25, p1 = half ? NP : 25;
        float acc = 0.f;
        const float* Hb = H + (size_t)b * NP * IRC * OP2 + o;
        for (int p = p0; p < p1; ++p) {
            int ph = p / PPOOL, pw = p - ph * PPOOL;
            const float* Hp = Hb + (size_t)p * IRC * OP2;
            int re = sre[ph], rs = srs[ph], ce = sce[pw], cs = scs[pw];
            float v = Hp[(size_t)(re * IW + ce) * OP2] - Hp[(size_t)(rs * IW + ce) * OP2]
                    - Hp[(size_t)(re * IW + cs) * OP2] + Hp[(size_t)(rs * IW + cs) * OP2];
            acc += v * sinv[p];
        }
        psum[half][o] = acc;
    }
    __syncthreads();
    if (t < NO) {
        float v = psum[0][t] + psum[1][t] + bias[t];
        sl[t] = v;
        if (t >= 80)
            out[(size_t)(4 * BATCH * NBOX) + ((size_t)b * NBOX + n) * (NCLS + 1) + (t - 80)] = v;
    }
    __syncthreads();
    if (t == 0) {
        float best = sl[80]; int mi = 0;
        for (int s = 1; s <= NCLS; ++s) {
            float v = sl[80 + s];
            if (v > best) { best = v; mi = s; }
        }
        smi = mi;
    }
    __syncthreads();
    if (t < 4) out[((size_t)b * NBOX + n) * 4 + t] = sl[smi + t];
}

extern "C" void kernel_launch(void* const* d_in, const int* in_sizes, int n_in,
                              void* d_out, int out_size, void* d_ws, size_t ws_size,
                              hipStream_t stream) {
    const float* fm    = (const float*)d_in[0];
    const float* boxes = (const float*)d_in[1];
    const float* fcw   = (const float*)d_in[2];
    const float* fcb   = (const float*)d_in[3];
    const float* lw    = (const float*)d_in[4];
    const float* lb    = (const float*)d_in[5];
    const float* sw    = (const float*)d_in[6];
    const float* sb    = (const float*)d_in[7];
    float* out = (float*)d_out;

    float* ws = (float*)d_ws;
    float* I    = ws;                                        // 2*512*768 = 786,432 f
    u32v4* Ahi  = (u32v4*)(I + (size_t)BATCH * CH * IRCP2);  // 57,344 frag-words
    u32v4* Amd  = Ahi + MFRAG * NSTEP_TOT * 64;
    float* bias = (float*)(Amd + MFRAG * NSTEP_TOT * 64);    // 128 f
    float* Wcp  = bias + 128;                                // 8 * S_WC f (90 MB)
    u32v4* Whi  = (u32v4*)(Wcp + (size_t)FSPLIT * S_WC);     // 351,232 frag-words
    u32v4* Wmd  = Whi + (size_t)NFRAG_H * 64;
    u32v4* Wlo  = Wmd + (size_t)NFRAG_H * 64;
    float* H    = (float*)(Wlo + (size_t)NFRAG_H * 64);      // 7,419,392 f
    // total ws ~= 142 MB

    hipLaunchKernelGGL(k_lt, dim3(224), dim3(256), 0, stream, lw, sw, Ahi, Amd);
    hipLaunchKernelGGL(k_integral, dim3(256), dim3(256), 0, stream, fm, I);
    hipLaunchKernelGGL(k_bias, dim3(104), dim3(256), 0, stream, lw, sw, fcb, lb, sb, bias);
    hipLaunchKernelGGL(k_wc, dim3(196, FSPLIT), dim3(256), 0, stream, fcw, Ahi, Amd, Wcp);
    hipLaunchKernelGGL(k_redsplit, dim3(NFRAG_H * 64 / 256), dim3(256), 0, stream, Wcp, Whi, Wmd, Wlo);
    hipLaunchKernelGGL(k_h, dim3(6, NP, BATCH), dim3(256), 0, stream, I, Whi, Wmd, Wlo, H);
    hipLaunchKernelGGL(k_out, dim3(NBOX, BATCH), dim3(256), 0, stream, boxes, H, bias, out);
}

// Round 6
// 262.046 us; speedup vs baseline: 3.6121x; 1.0705x over previous
//
#include <hip/hip_runtime.h>

#define BATCH 2
#define NBOX 500
#define CH 512
#define HFD 25
#define IW 26
#define IRC 676            // 26*26
#define IRCP2 768          // padded channel stride (covers rc-tile overreach)
#define PPOOL 7
#define NP 49
#define NCLS 20
#define NO 101             // 80 loc + 21 score
#define OP2 112            // o padded to 7*16
#define MFRAG 7
#define KD 25088
#define FDIM 4096
#define NSTEP_TOT 128      // FDIM/32
#define FSPLIT 8
#define WCSTEPS 16         // steps per f-chunk = 512/32
#define S_WC ((size_t)KD * OP2)   // 2,809,856
#define NFRAG_H (NP * 16 * MFRAG) // 5488 fragments per table for k_h

typedef __attribute__((ext_vector_type(4))) float f32x4;
typedef __attribute__((ext_vector_type(8))) short bf16x8;
typedef __attribute__((ext_vector_type(4))) unsigned int u32v4;

#define MFMA16 __builtin_amdgcn_mfma_f32_16x16x32_bf16

typedef __attribute__((address_space(1))) const unsigned int guint;
typedef __attribute__((address_space(3))) unsigned int luint;
#define GLL16(G, L) __builtin_amdgcn_global_load_lds((guint*)(G), (luint*)(L), 16, 0, 0)

// ---- 2-way split of an fp32 pair: hi = trunc-bf16(v), mid = RN-bf16(v-hi).
#define SPLIT2PK(V0, V1, HW, MW)                                       \
  {                                                                    \
    unsigned u0_ = __float_as_uint(V0), u1_ = __float_as_uint(V1);     \
    HW = (u0_ >> 16) | (u1_ & 0xffff0000u);                            \
    float r0_ = (V0) - __uint_as_float(u0_ & 0xffff0000u);             \
    float r1_ = (V1) - __uint_as_float(u1_ & 0xffff0000u);             \
    unsigned m0_ = __float_as_uint(r0_), m1_ = __float_as_uint(r1_);   \
    m0_ += 0x7fffu + ((m0_ >> 16) & 1u);                               \
    m1_ += 0x7fffu + ((m1_ >> 16) & 1u);                               \
    MW = (m0_ >> 16) | (m1_ & 0xffff0000u);                            \
  }

// ---- cheap variant: hi trunc, mid = trunc-bf16(v-hi); |rho| <= 2^-16|v| ----
#define SPLIT2T(V0, V1, HW, MW)                                        \
  {                                                                    \
    unsigned u0_ = __float_as_uint(V0), u1_ = __float_as_uint(V1);     \
    HW = (u0_ >> 16) | (u1_ & 0xffff0000u);                            \
    float r0_ = (V0) - __uint_as_float(u0_ & 0xffff0000u);             \
    float r1_ = (V1) - __uint_as_float(u1_ & 0xffff0000u);             \
    MW = (__float_as_uint(r0_) >> 16) |                                \
         (__float_as_uint(r1_) & 0xffff0000u);                         \
  }

// ---- exact 3-way truncation split (24-bit mantissa = 8+8+8) ----
#define SPLIT3PK(V0, V1, HW, MW, LW)                                   \
  {                                                                    \
    unsigned u0_ = __float_as_uint(V0), u1_ = __float_as_uint(V1);     \
    HW = (u0_ >> 16) | (u1_ & 0xffff0000u);                            \
    float r0_ = (V0) - __uint_as_float(u0_ & 0xffff0000u);             \
    float r1_ = (V1) - __uint_as_float(u1_ & 0xffff0000u);             \
    unsigned m0_ = __float_as_uint(r0_), m1_ = __float_as_uint(r1_);   \
    MW = (m0_ >> 16) | (m1_ & 0xffff0000u);                            \
    float s0_ = r0_ - __uint_as_float(m0_ & 0xffff0000u);              \
    float s1_ = r1_ - __uint_as_float(m1_ & 0xffff0000u);              \
    LW = (__float_as_uint(s0_) >> 16) |                                \
         (__float_as_uint(s1_) & 0xffff0000u);                         \
  }

// ---------------- A-tables: L=[l_w;s_w] -> MFMA A-frags, 2-way split -------
// Ahi[(mf*128 + s)*64 + lane] = 8 bf16 = A[o=mf*16+(l&15)][f=s*32+(l>>4)*8+j]
__global__ void k_lt(const float* __restrict__ lw, const float* __restrict__ sw,
                     u32v4* __restrict__ Ahi, u32v4* __restrict__ Amd) {
    int t = blockIdx.x * 256 + threadIdx.x;
    if (t >= MFRAG * NSTEP_TOT * 64) return;
    int lane = t & 63;
    int wv = t >> 6;                 // (mf*128 + s)
    int s = wv & 127, mf = wv >> 7;
    int o = mf * 16 + (lane & 15);
    int f0 = s * 32 + (lane >> 4) * 8;
    float v[8];
    const float* row = nullptr;
    if (o < 80) row = lw + (size_t)o * FDIM;
    else if (o < NO) row = sw + (size_t)(o - 80) * FDIM;
    #pragma unroll
    for (int j = 0; j < 8; ++j) v[j] = row ? row[f0 + j] : 0.f;
    u32v4 hw, mw;
    #pragma unroll
    for (int w = 0; w < 4; ++w)
        SPLIT2PK(v[2 * w], v[2 * w + 1], hw[w], mw[w]);
    Ahi[(size_t)wv * 64 + lane] = hw;
    Amd[(size_t)wv * 64 + lane] = mw;
}

// ---------------- integral image, c-major, padded stride 768 ---------------
__global__ void k_integral(const float* __restrict__ fm, float* __restrict__ I) {
    int gtid = blockIdx.x * blockDim.x + threadIdx.x;
    int wid = gtid >> 6;
    int lane = gtid & 63;
    if (wid >= BATCH * CH) return;
    const float* src = fm + (size_t)wid * (HFD * HFD);
    float* dst = I + (size_t)wid * IRCP2;
    if (lane < IW) dst[lane] = 0.f;
    if (lane >= 1 && lane < IW) dst[lane * IW] = 0.f;
    int c = lane;
    float acc = 0.f;
    for (int r = 0; r < HFD; ++r) {
        float v = (c < HFD) ? src[r * HFD + c] : 0.f;
        #pragma unroll
        for (int d = 1; d < 32; d <<= 1) {
            float t = __shfl_up(v, d, 64);
            if (lane >= d) v += t;
        }
        acc += v;
        if (c < HFD) dst[(r + 1) * IW + (c + 1)] = acc;
    }
}

// ---------------- bias'[o] = L[o]·fc_b + {l_b|s_b}[o] ----------------------
__global__ void k_bias(const float* __restrict__ lw, const float* __restrict__ sw,
                       const float* __restrict__ fcb, const float* __restrict__ lb,
                       const float* __restrict__ sb, float* __restrict__ bias) {
    int o = blockIdx.x;
    __shared__ float red[256];
    float s = 0.f;
    if (o < NO) {
        const float* row = (o < 80) ? (lw + (size_t)o * FDIM) : (sw + (size_t)(o - 80) * FDIM);
        for (int f = threadIdx.x; f < FDIM; f += 256) s += row[f] * fcb[f];
    }
    red[threadIdx.x] = s;
    __syncthreads();
    for (int st = 128; st > 0; st >>= 1) {
        if ((int)threadIdx.x < st) red[threadIdx.x] += red[threadIdx.x + st];
        __syncthreads();
    }
    if (threadIdx.x == 0) {
        float bv = 0.f;
        if (o < 80) bv = red[0] + lb[o];
        else if (o < NO) bv = red[0] + sb[o - 80];
        bias[o] = bv;
    }
}

// ---------------- Wc partials via MFMA, LDS-staged pipeline ----------------
// Wcp[fs][k][o] = sum_{f in chunk fs} L[o][f] * W1[f][k]
// grid (196, 8). Block: 4 waves, 128 k, f-step 32. Tile [32f][128k] fp32,
// double-buffered (32 KB), staged via global_load_lds dwordx4 with XOR
// swizzle on the GLOBAL source (LDS dest linear, rule #21):
//   LDS elem (row, kbyte) holds W1[f0+row][k0 + ((kbyte ^ ((row>>3)&3)<<5)>>2)]
// Read side applies the same XOR -> <=2-way bank conflicts (free).
#define WC_STAGE(S, DB)                                                       \
  {                                                                           \
    const float* gs_ = gsrc0 + (size_t)((S) * 32) * KD;                       \
    float* lb_ = &Bs[DB][w * 1024];                                           \
    _Pragma("unroll")                                                         \
    for (int i_ = 0; i_ < 4; ++i_)                                            \
      GLL16(gs_ + (size_t)(i_ * 2) * KD, lb_ + i_ * 256);                     \
  }

#define WC_STEP(S, DB)                                                        \
  {                                                                           \
    u32v4 ah[MFRAG], am[MFRAG];                                               \
    _Pragma("unroll")                                                         \
    for (int mf = 0; mf < MFRAG; ++mf) {                                      \
      size_t ai = (size_t)((mf * 128 + fs * WCSTEPS + (S)) * 64 + lane);      \
      ah[mf] = Ahi[ai]; am[mf] = Amd[ai];                                     \
    }                                                                         \
    const char* bs_ = (const char*)&Bs[DB][0];                                \
    float bv0[8], bv1[8];                                                     \
    _Pragma("unroll")                                                         \
    for (int j = 0; j < 8; ++j) {                                             \
      bv0[j] = *(const float*)(bs_ + rb + j * 512 + kb0);                     \
      bv1[j] = *(const float*)(bs_ + rb + j * 512 + kb1);                     \
    }                                                                         \
    u32v4 bh0w, bm0w, bh1w, bm1w;                                             \
    _Pragma("unroll")                                                         \
    for (int w_ = 0; w_ < 4; ++w_) {                                          \
      SPLIT2T(bv0[2 * w_], bv0[2 * w_ + 1], bh0w[w_], bm0w[w_]);              \
      SPLIT2T(bv1[2 * w_], bv1[2 * w_ + 1], bh1w[w_], bm1w[w_]);              \
    }                                                                         \
    bf16x8 bh0 = __builtin_bit_cast(bf16x8, bh0w);                            \
    bf16x8 bm0 = __builtin_bit_cast(bf16x8, bm0w);                            \
    bf16x8 bh1 = __builtin_bit_cast(bf16x8, bh1w);                            \
    bf16x8 bm1 = __builtin_bit_cast(bf16x8, bm1w);                            \
    _Pragma("unroll")                                                         \
    for (int mf = 0; mf < MFRAG; ++mf) {                                      \
      bf16x8 a_h = __builtin_bit_cast(bf16x8, ah[mf]);                        \
      bf16x8 a_m = __builtin_bit_cast(bf16x8, am[mf]);                        \
      acc[mf][0] = MFMA16(a_h, bh0, acc[mf][0], 0, 0, 0);                     \
      acc[mf][0] = MFMA16(a_m, bh0, acc[mf][0], 0, 0, 0);                     \
      acc[mf][0] = MFMA16(a_h, bm0, acc[mf][0], 0, 0, 0);                     \
      acc[mf][1] = MFMA16(a_h, bh1, acc[mf][1], 0, 0, 0);                     \
      acc[mf][1] = MFMA16(a_m, bh1, acc[mf][1], 0, 0, 0);                     \
      acc[mf][1] = MFMA16(a_h, bm1, acc[mf][1], 0, 0, 0);                     \
    }                                                                         \
  }

__global__ void __launch_bounds__(256, 3) k_wc(const float* __restrict__ W1,
                                               const u32v4* __restrict__ Ahi,
                                               const u32v4* __restrict__ Amd,
                                               float* __restrict__ Wcp) {
    __shared__ float Bs[2][32 * 128];
    int lane = threadIdx.x & 63;
    int w = threadIdx.x >> 6;        // wave 0..3
    int kb = blockIdx.x;             // 0..195
    int fs = blockIdx.y;             // 0..7
    int k0 = kb * 128;
    int col = lane & 15, rowg = lane >> 4;

    // staging source (per-lane): row = fs*512 + s*32 + w*8 + i*2 + (lane>=32)
    int lin = lane & 31, hi = lane >> 5;
    int skel = (((lin * 16) ^ ((w & 3) << 5)) >> 2);
    const float* gsrc0 = W1 + ((size_t)(fs * 512) + w * 8 + hi) * KD + k0 + skel;

    // fragment read addresses (swizzled)
    unsigned rb = (unsigned)(rowg * 4096);                         // rowg*8 rows * 512B
    unsigned kb0 = ((unsigned)((w * 32 + col) * 4)) ^ ((unsigned)rowg << 5);
    unsigned kb1 = ((unsigned)((w * 32 + col + 16) * 4)) ^ ((unsigned)rowg << 5);

    f32x4 acc[MFRAG][2];
    #pragma unroll
    for (int mf = 0; mf < MFRAG; ++mf) {
        acc[mf][0] = (f32x4){0.f, 0.f, 0.f, 0.f};
        acc[mf][1] = (f32x4){0.f, 0.f, 0.f, 0.f};
    }

    WC_STAGE(0, 0);
    __syncthreads();
    for (int s = 0; s < WCSTEPS; ++s) {
        int db = s & 1;
        if (s + 1 < WCSTEPS) WC_STAGE(s + 1, db ^ 1);
        WC_STEP(s, db);
        __syncthreads();
    }

    float* wp = Wcp + (size_t)fs * S_WC;
    #pragma unroll
    for (int mf = 0; mf < MFRAG; ++mf)
        #pragma unroll
        for (int nf = 0; nf < 2; ++nf) {
            size_t k = (size_t)k0 + w * 32 + nf * 16 + col;
            int o = mf * 16 + (rowg << 2);
            *(f32x4*)(wp + k * OP2 + o) = acc[mf][nf];
        }
}

// ---------------- fused: reduce 8 f-chunks + 3-way split -> k_h A-tables ---
__global__ void k_redsplit(const float* __restrict__ Wcp, u32v4* __restrict__ Whi,
                           u32v4* __restrict__ Wmd, u32v4* __restrict__ Wlo) {
    int t = blockIdx.x * 256 + threadIdx.x;   // over NFRAG_H*64
    int lane = t & 63;
    int fi = t >> 6;
    int p = fi / (16 * MFRAG);
    int rem = fi - p * (16 * MFRAG);
    int cs = rem / MFRAG, mf = rem - cs * MFRAG;
    int o = mf * 16 + (lane & 15);
    int c0 = cs * 32 + (lane >> 4) * 8;
    float v[8];
    #pragma unroll
    for (int j = 0; j < 8; ++j) {
        size_t base = ((size_t)(c0 + j) * NP + p) * OP2 + o;
        float s = 0.f;
        #pragma unroll
        for (int i = 0; i < FSPLIT; ++i) s += Wcp[base + (size_t)i * S_WC];
        v[j] = s;
    }
    u32v4 hw, mw, lww;
    #pragma unroll
    for (int w = 0; w < 4; ++w)
        SPLIT3PK(v[2 * w], v[2 * w + 1], hw[w], mw[w], lww[w]);
    Whi[(size_t)fi * 64 + lane] = hw;
    Wmd[(size_t)fi * 64 + lane] = mw;
    Wlo[(size_t)fi * 64 + lane] = lww;
}

// ---------------- H[b][p][rc][o] = sum_c Wc[c*49+p][o] * I[b][c][rc] -------
// MFMA, 6-product (H feeds corner-difference cancellation -> need ~2^-24 rel).
#define KH_STEP(CUR, NXT, S)                                                  \
  {                                                                           \
    if ((S) + 1 < 16) {                                                       \
      _Pragma("unroll")                                                       \
      for (int nf = 0; nf < 2; ++nf)                                          \
        _Pragma("unroll")                                                     \
        for (int j = 0; j < 8; ++j)                                           \
          NXT[nf][j] = Ib[(size_t)(((S) + 1) * 32 + rowg * 8 + j) * IRCP2 + nf * 16]; \
    }                                                                         \
    bf16x8 bh[2], bm[2], bl[2];                                               \
    _Pragma("unroll")                                                         \
    for (int nf = 0; nf < 2; ++nf) {                                          \
      u32v4 bhw, bmw, blw;                                                    \
      _Pragma("unroll")                                                       \
      for (int w_ = 0; w_ < 4; ++w_)                                          \
        SPLIT3PK(CUR[nf][2 * w_], CUR[nf][2 * w_ + 1], bhw[w_], bmw[w_], blw[w_]); \
      bh[nf] = __builtin_bit_cast(bf16x8, bhw);                               \
      bm[nf] = __builtin_bit_cast(bf16x8, bmw);                               \
      bl[nf] = __builtin_bit_cast(bf16x8, blw);                               \
    }                                                                         \
    _Pragma("unroll")                                                         \
    for (int mf = 0; mf < MFRAG; ++mf) {                                      \
      size_t ai = (size_t)(((p * 16 + (S)) * MFRAG + mf) * 64 + lane);        \
      bf16x8 a_h = __builtin_bit_cast(bf16x8, Whi[ai]);                       \
      bf16x8 a_m = __builtin_bit_cast(bf16x8, Wmd[ai]);                       \
      bf16x8 a_l = __builtin_bit_cast(bf16x8, Wlo[ai]);                       \
      _Pragma("unroll")                                                       \
      for (int nf = 0; nf < 2; ++nf) {                                        \
        acc[mf][nf] = MFMA16(a_h, bh[nf], acc[mf][nf], 0, 0, 0);              \
        acc[mf][nf] = MFMA16(a_m, bh[nf], acc[mf][nf], 0, 0, 0);              \
        acc[mf][nf] = MFMA16(a_h, bm[nf], acc[mf][nf], 0, 0, 0);              \
        acc[mf][nf] = MFMA16(a_m, bm[nf], acc[mf][nf], 0, 0, 0);              \
        acc[mf][nf] = MFMA16(a_l, bh[nf], acc[mf][nf], 0, 0, 0);              \
        acc[mf][nf] = MFMA16(a_h, bl[nf], acc[mf][nf], 0, 0, 0);              \
      }                                                                       \
    }                                                                         \
  }

__global__ void __launch_bounds__(256, 2) k_h(const float* __restrict__ I,
                                              const u32v4* __restrict__ Whi,
                                              const u32v4* __restrict__ Wmd,
                                              const u32v4* __restrict__ Wlo,
                                              float* __restrict__ H) {
    int lane = threadIdx.x & 63;
    int w = threadIdx.x >> 6;
    int rcb = blockIdx.x, p = blockIdx.y, b = blockIdx.z;
    int col = lane & 15, rowg = lane >> 4;
    int rcw = rcb * 128 + w * 32;                 // wave's rc base
    const float* Ib = I + (size_t)b * CH * IRCP2 + rcw + col;

    f32x4 acc[MFRAG][2];
    #pragma unroll
    for (int mf = 0; mf < MFRAG; ++mf) {
        acc[mf][0] = (f32x4){0.f, 0.f, 0.f, 0.f};
        acc[mf][1] = (f32x4){0.f, 0.f, 0.f, 0.f};
    }
    float ib0[2][8], ib1[2][8];
    #pragma unroll
    for (int nf = 0; nf < 2; ++nf)
        #pragma unroll
        for (int j = 0; j < 8; ++j)
            ib0[nf][j] = Ib[(size_t)(rowg * 8 + j) * IRCP2 + nf * 16];

    for (int s = 0; s < 16; s += 2) {
        KH_STEP(ib0, ib1, s);
        KH_STEP(ib1, ib0, s + 1);
    }

    #pragma unroll
    for (int mf = 0; mf < MFRAG; ++mf)
        #pragma unroll
        for (int nf = 0; nf < 2; ++nf) {
            int rc = rcw + nf * 16 + col;
            if (rc < IRC) {
                float* hp = H + (((size_t)(b * NP + p)) * IRC + rc) * OP2
                            + mf * 16 + rowg * 4;
                *(f32x4*)hp = acc[mf][nf];
            }
        }
}

// ---------------- per-box gather + bias + argmax + outputs -----------------
__global__ void __launch_bounds__(256) k_out(const float* __restrict__ boxes,
                                             const float* __restrict__ H,
                                             const float* __restrict__ bias,
                                             float* __restrict__ out) {
    int n = blockIdx.x, b = blockIdx.y;
    int t = threadIdx.x;
    __shared__ int srs[PPOOL], sre[PPOOL], scs[PPOOL], sce[PPOOL];
    __shared__ float sinv[NP];
    __shared__ float psum[2][NO];
    __shared__ float sl[NO];
    __shared__ int smi;
    const float* bx = boxes + ((size_t)b * NBOX + n) * 4;
    if (t < PPOOL) {
        int r0 = (int)(bx[0] / 32.0f);
        int c0 = (int)(bx[1] / 32.0f);
        int r1 = (int)(bx[2] / 32.0f);
        int c1 = (int)(bx[3] / 32.0f);
        int sr = r1 - r0, sc = c1 - c0;
        srs[t] = r0 + (t * sr) / PPOOL;
        sre[t] = r0 + ((t + 1) * sr + PPOOL - 1) / PPOOL;
        scs[t] = c0 + (t * sc) / PPOOL;
        sce[t] = c0 + ((t + 1) * sc + PPOOL - 1) / PPOOL;
    }
    __syncthreads();
    if (t < NP) {
        int ph = t / PPOOL, pw = t - ph * PPOOL;
        sinv[t] = 1.0f / (float)((sre[ph] - srs[ph]) * (sce[pw] - scs[pw]));
    }
    __syncthreads();
    int o = t & 127, half = t >> 7;
    if (o < NO) {
        int p0 = half * 25, p1 = half ? NP : 25;
        float acc = 0.f;
        const float* Hb = H + (size_t)b * NP * IRC * OP2 + o;
        for (int p = p0; p < p1; ++p) {
            int ph = p / PPOOL, pw = p - ph * PPOOL;
            const float* Hp = Hb + (size_t)p * IRC * OP2;
            int re = sre[ph], rs = srs[ph], ce = sce[pw], cs = scs[pw];
            float v = Hp[(size_t)(re * IW + ce) * OP2] - Hp[(size_t)(rs * IW + ce) * OP2]
                    - Hp[(size_t)(re * IW + cs) * OP2] + Hp[(size_t)(rs * IW + cs) * OP2];
            acc += v * sinv[p];
        }
        psum[half][o] = acc;
    }
    __syncthreads();
    if (t < NO) {
        float v = psum[0][t] + psum[1][t] + bias[t];
        sl[t] = v;
        if (t >= 80)
            out[(size_t)(4 * BATCH * NBOX) + ((size_t)b * NBOX + n) * (NCLS + 1) + (t - 80)] = v;
    }
    __syncthreads();
    if (t == 0) {
        float best = sl[80]; int mi = 0;
        for (int s = 1; s <= NCLS; ++s) {
            float v = sl[80 + s];
            if (v > best) { best = v; mi = s; }
        }
        smi = mi;
    }
    __syncthreads();
    if (t < 4) out[((size_t)b * NBOX + n) * 4 + t] = sl[smi + t];
}

extern "C" void kernel_launch(void* const* d_in, const int* in_sizes, int n_in,
                              void* d_out, int out_size, void* d_ws, size_t ws_size,
                              hipStream_t stream) {
    const float* fm    = (const float*)d_in[0];
    const float* boxes = (const float*)d_in[1];
    const float* fcw   = (const float*)d_in[2];
    const float* fcb   = (const float*)d_in[3];
    const float* lw    = (const float*)d_in[4];
    const float* lb    = (const float*)d_in[5];
    const float* sw    = (const float*)d_in[6];
    const float* sb    = (const float*)d_in[7];
    float* out = (float*)d_out;

    float* ws = (float*)d_ws;
    float* I    = ws;                                        // 786,432 f
    u32v4* Ahi  = (u32v4*)(I + (size_t)BATCH * CH * IRCP2);  // 57,344 frag-words
    u32v4* Amd  = Ahi + MFRAG * NSTEP_TOT * 64;
    float* bias = (float*)(Amd + MFRAG * NSTEP_TOT * 64);    // 128 f
    float* Wcp  = bias + 128;                                // 8 * S_WC f (90 MB)
    u32v4* Whi  = (u32v4*)(Wcp + (size_t)FSPLIT * S_WC);     // 351,232 frag-words
    u32v4* Wmd  = Whi + (size_t)NFRAG_H * 64;
    u32v4* Wlo  = Wmd + (size_t)NFRAG_H * 64;
    float* H    = (float*)(Wlo + (size_t)NFRAG_H * 64);      // 7,419,392 f
    // total ws ~= 142 MB

    hipLaunchKernelGGL(k_lt, dim3(224), dim3(256), 0, stream, lw, sw, Ahi, Amd);
    hipLaunchKernelGGL(k_integral, dim3(256), dim3(256), 0, stream, fm, I);
    hipLaunchKernelGGL(k_bias, dim3(104), dim3(256), 0, stream, lw, sw, fcb, lb, sb, bias);
    hipLaunchKernelGGL(k_wc, dim3(196, FSPLIT), dim3(256), 0, stream, fcw, Ahi, Amd, Wcp);
    hipLaunchKernelGGL(k_redsplit, dim3(NFRAG_H * 64 / 256), dim3(256), 0, stream, Wcp, Whi, Wmd, Wlo);
    hipLaunchKernelGGL(k_h, dim3(6, NP, BATCH), dim3(256), 0, stream, I, Whi, Wmd, Wlo, H);
    hipLaunchKernelGGL(k_out, dim3(NBOX, BATCH), dim3(256), 0, stream, boxes, H, bias, out);
}

// Round 7
// 250.675 us; speedup vs baseline: 3.7760x; 1.0454x over previous
//
#include <hip/hip_runtime.h>

#define BATCH 2
#define NBOX 500
#define CH 512
#define HFD 25
#define IW 26
#define IRC 676            // 26*26
#define IRCP2 768          // padded channel stride (covers rc-tile overreach)
#define PPOOL 7
#define NP 49
#define NCLS 20
#define NO 101             // 80 loc + 21 score
#define OP2 112            // o padded to 7*16
#define MFRAG 7
#define KD 25088
#define FDIM 4096
#define NSTEP_TOT 128      // FDIM/32
#define FSPLIT 8
#define WCSTEPS 16         // steps per f-chunk = 512/32
#define S_WC ((size_t)KD * OP2)   // 2,809,856
#define NFRAG_H (NP * 16 * MFRAG) // 5488 fragments per table for k_h

typedef __attribute__((ext_vector_type(4))) float f32x4;
typedef __attribute__((ext_vector_type(8))) short bf16x8;
typedef __attribute__((ext_vector_type(4))) unsigned int u32v4;

#define MFMA16 __builtin_amdgcn_mfma_f32_16x16x32_bf16

typedef __attribute__((address_space(1))) const unsigned int guint;
typedef __attribute__((address_space(3))) unsigned int luint;
#define GLL16(G, L) __builtin_amdgcn_global_load_lds((guint*)(G), (luint*)(L), 16, 0, 0)

// ---- 2-way split of an fp32 pair: hi = trunc-bf16(v), mid = RN-bf16(v-hi).
#define SPLIT2PK(V0, V1, HW, MW)                                       \
  {                                                                    \
    unsigned u0_ = __float_as_uint(V0), u1_ = __float_as_uint(V1);     \
    HW = (u0_ >> 16) | (u1_ & 0xffff0000u);                            \
    float r0_ = (V0) - __uint_as_float(u0_ & 0xffff0000u);             \
    float r1_ = (V1) - __uint_as_float(u1_ & 0xffff0000u);             \
    unsigned m0_ = __float_as_uint(r0_), m1_ = __float_as_uint(r1_);   \
    m0_ += 0x7fffu + ((m0_ >> 16) & 1u);                               \
    m1_ += 0x7fffu + ((m1_ >> 16) & 1u);                               \
    MW = (m0_ >> 16) | (m1_ & 0xffff0000u);                            \
  }

// ---- cheap variant: hi trunc, mid = trunc-bf16(v-hi); |rho| <= 2^-16|v| ----
#define SPLIT2T(V0, V1, HW, MW)                                        \
  {                                                                    \
    unsigned u0_ = __float_as_uint(V0), u1_ = __float_as_uint(V1);     \
    HW = (u0_ >> 16) | (u1_ & 0xffff0000u);                            \
    float r0_ = (V0) - __uint_as_float(u0_ & 0xffff0000u);             \
    float r1_ = (V1) - __uint_as_float(u1_ & 0xffff0000u);             \
    MW = (__float_as_uint(r0_) >> 16) |                                \
         (__float_as_uint(r1_) & 0xffff0000u);                         \
  }

// ---- exact 3-way truncation split (24-bit mantissa = 8+8+8) ----
#define SPLIT3PK(V0, V1, HW, MW, LW)                                   \
  {                                                                    \
    unsigned u0_ = __float_as_uint(V0), u1_ = __float_as_uint(V1);     \
    HW = (u0_ >> 16) | (u1_ & 0xffff0000u);                            \
    float r0_ = (V0) - __uint_as_float(u0_ & 0xffff0000u);             \
    float r1_ = (V1) - __uint_as_float(u1_ & 0xffff0000u);             \
    unsigned m0_ = __float_as_uint(r0_), m1_ = __float_as_uint(r1_);   \
    MW = (m0_ >> 16) | (m1_ & 0xffff0000u);                            \
    float s0_ = r0_ - __uint_as_float(m0_ & 0xffff0000u);              \
    float s1_ = r1_ - __uint_as_float(m1_ & 0xffff0000u);              \
    LW = (__float_as_uint(s0_) >> 16) |                                \
         (__float_as_uint(s1_) & 0xffff0000u);                         \
  }

// ---------------- A-tables: L=[l_w;s_w] -> MFMA A-frags, 2-way split -------
// Ahi[(mf*128 + s)*64 + lane] = 8 bf16 = A[o=mf*16+(l&15)][f=s*32+(l>>4)*8+j]
__global__ void k_lt(const float* __restrict__ lw, const float* __restrict__ sw,
                     u32v4* __restrict__ Ahi, u32v4* __restrict__ Amd) {
    int t = blockIdx.x * 256 + threadIdx.x;
    if (t >= MFRAG * NSTEP_TOT * 64) return;
    int lane = t & 63;
    int wv = t >> 6;                 // (mf*128 + s)
    int s = wv & 127, mf = wv >> 7;
    int o = mf * 16 + (lane & 15);
    int f0 = s * 32 + (lane >> 4) * 8;
    float v[8];
    const float* row = nullptr;
    if (o < 80) row = lw + (size_t)o * FDIM;
    else if (o < NO) row = sw + (size_t)(o - 80) * FDIM;
    #pragma unroll
    for (int j = 0; j < 8; ++j) v[j] = row ? row[f0 + j] : 0.f;
    u32v4 hw, mw;
    #pragma unroll
    for (int w = 0; w < 4; ++w)
        SPLIT2PK(v[2 * w], v[2 * w + 1], hw[w], mw[w]);
    Ahi[(size_t)wv * 64 + lane] = hw;
    Amd[(size_t)wv * 64 + lane] = mw;
}

// ---------------- integral image, c-major, padded stride 768 ---------------
__global__ void k_integral(const float* __restrict__ fm, float* __restrict__ I) {
    int gtid = blockIdx.x * blockDim.x + threadIdx.x;
    int wid = gtid >> 6;
    int lane = gtid & 63;
    if (wid >= BATCH * CH) return;
    const float* src = fm + (size_t)wid * (HFD * HFD);
    float* dst = I + (size_t)wid * IRCP2;
    if (lane < IW) dst[lane] = 0.f;
    if (lane >= 1 && lane < IW) dst[lane * IW] = 0.f;
    int c = lane;
    float acc = 0.f;
    for (int r = 0; r < HFD; ++r) {
        float v = (c < HFD) ? src[r * HFD + c] : 0.f;
        #pragma unroll
        for (int d = 1; d < 32; d <<= 1) {
            float t = __shfl_up(v, d, 64);
            if (lane >= d) v += t;
        }
        acc += v;
        if (c < HFD) dst[(r + 1) * IW + (c + 1)] = acc;
    }
}

// ---------------- bias'[o] = L[o]·fc_b + {l_b|s_b}[o] ----------------------
__global__ void k_bias(const float* __restrict__ lw, const float* __restrict__ sw,
                       const float* __restrict__ fcb, const float* __restrict__ lb,
                       const float* __restrict__ sb, float* __restrict__ bias) {
    int o = blockIdx.x;
    __shared__ float red[256];
    float s = 0.f;
    if (o < NO) {
        const float* row = (o < 80) ? (lw + (size_t)o * FDIM) : (sw + (size_t)(o - 80) * FDIM);
        for (int f = threadIdx.x; f < FDIM; f += 256) s += row[f] * fcb[f];
    }
    red[threadIdx.x] = s;
    __syncthreads();
    for (int st = 128; st > 0; st >>= 1) {
        if ((int)threadIdx.x < st) red[threadIdx.x] += red[threadIdx.x + st];
        __syncthreads();
    }
    if (threadIdx.x == 0) {
        float bv = 0.f;
        if (o < 80) bv = red[0] + lb[o];
        else if (o < NO) bv = red[0] + sb[o - 80];
        bias[o] = bv;
    }
}

// ---------------- Wc partials via MFMA, LDS-staged, wave-k = 64 ------------
// Wcp[fs][k][o] = sum_{f in chunk fs} L[o][f] * W1[f][k]
// grid (98, 8): x = k-block (256 k), y = f-chunk(512). 4 waves; wave covers
// 64 k (4 nf) so the per-step A-fragment loads amortize over 2x the FLOPs
// (A-table L2 traffic was the round-6 bottleneck). Tile [32f][256k] fp32,
// double-buffered (64 KB), staged via global_load_lds dwordx4 with XOR
// swizzle on the GLOBAL source (LDS dest linear):
//   LDS (row, kbyte) holds W1[f0+row][k0 + ((kbyte ^ (((row>>3)&3)<<6))>>2)]
// Read applies same XOR -> 2 lanes/bank (free).
#define WC_STAGE(S, DB)                                                       \
  {                                                                           \
    const float* gb_ = W1 + (size_t)(fs * 512 + (S) * 32 + w) * KD + k0;      \
    _Pragma("unroll")                                                         \
    for (int i_ = 0; i_ < 8; ++i_) {                                          \
      unsigned gc_ = (lb16 ^ ((unsigned)(i_ >> 1) << 6)) >> 2;                \
      GLL16(gb_ + (size_t)(4 * i_) * KD + gc_,                                \
            &Bs[DB][i_ * 1024 + w * 256]);                                    \
    }                                                                         \
  }

#define WC_STEP(S, DB)                                                        \
  {                                                                           \
    u32v4 ah[MFRAG], am[MFRAG];                                               \
    _Pragma("unroll")                                                         \
    for (int mf = 0; mf < MFRAG; ++mf) {                                      \
      size_t ai = (size_t)((mf * 128 + fs * WCSTEPS + (S)) * 64 + lane);      \
      ah[mf] = Ahi[ai]; am[mf] = Amd[ai];                                     \
    }                                                                         \
    const char* bs_ = (const char*)&Bs[DB][0];                                \
    _Pragma("unroll")                                                         \
    for (int nf = 0; nf < 4; ++nf) {                                          \
      float bv[8];                                                            \
      _Pragma("unroll")                                                       \
      for (int j = 0; j < 8; ++j)                                             \
        bv[j] = *(const float*)(bs_ + (rowg * 8 + j) * 1024 + kb[nf]);        \
      u32v4 bhw, bmw;                                                         \
      _Pragma("unroll")                                                       \
      for (int w_ = 0; w_ < 4; ++w_)                                          \
        SPLIT2T(bv[2 * w_], bv[2 * w_ + 1], bhw[w_], bmw[w_]);                \
      bf16x8 bh = __builtin_bit_cast(bf16x8, bhw);                            \
      bf16x8 bm = __builtin_bit_cast(bf16x8, bmw);                            \
      _Pragma("unroll")                                                       \
      for (int mf = 0; mf < MFRAG; ++mf) {                                    \
        bf16x8 a_h = __builtin_bit_cast(bf16x8, ah[mf]);                      \
        bf16x8 a_m = __builtin_bit_cast(bf16x8, am[mf]);                      \
        acc[mf][nf] = MFMA16(a_h, bh, acc[mf][nf], 0, 0, 0);                  \
        acc[mf][nf] = MFMA16(a_m, bh, acc[mf][nf], 0, 0, 0);                  \
        acc[mf][nf] = MFMA16(a_h, bm, acc[mf][nf], 0, 0, 0);                  \
      }                                                                       \
    }                                                                         \
  }

__global__ void __launch_bounds__(256, 2) k_wc(const float* __restrict__ W1,
                                               const u32v4* __restrict__ Ahi,
                                               const u32v4* __restrict__ Amd,
                                               float* __restrict__ Wcp) {
    __shared__ float Bs[2][32 * 256];
    int lane = threadIdx.x & 63;
    int w = threadIdx.x >> 6;        // wave 0..3
    int kblk = blockIdx.x;           // 0..97
    int fs = blockIdx.y;             // 0..7
    int k0 = kblk * 256;
    int col = lane & 15, rowg = lane >> 4;
    unsigned lb16 = (unsigned)lane * 16;

    unsigned kb[4];
    #pragma unroll
    for (int nf = 0; nf < 4; ++nf)
        kb[nf] = ((unsigned)((w * 64 + nf * 16 + col) * 4)) ^ ((unsigned)rowg << 6);

    f32x4 acc[MFRAG][4];
    #pragma unroll
    for (int mf = 0; mf < MFRAG; ++mf)
        #pragma unroll
        for (int nf = 0; nf < 4; ++nf)
            acc[mf][nf] = (f32x4){0.f, 0.f, 0.f, 0.f};

    WC_STAGE(0, 0);
    __syncthreads();
    for (int s = 0; s < WCSTEPS; ++s) {
        int db = s & 1;
        if (s + 1 < WCSTEPS) WC_STAGE(s + 1, db ^ 1);
        WC_STEP(s, db);
        __syncthreads();
    }

    float* wp = Wcp + (size_t)fs * S_WC;
    #pragma unroll
    for (int mf = 0; mf < MFRAG; ++mf)
        #pragma unroll
        for (int nf = 0; nf < 4; ++nf) {
            size_t k = (size_t)k0 + w * 64 + nf * 16 + col;
            int o = mf * 16 + (rowg << 2);
            *(f32x4*)(wp + k * OP2 + o) = acc[mf][nf];
        }
}

// ---------------- fused: reduce 8 f-chunks + 3-way split -> k_h A-tables ---
__global__ void k_redsplit(const float* __restrict__ Wcp, u32v4* __restrict__ Whi,
                           u32v4* __restrict__ Wmd, u32v4* __restrict__ Wlo) {
    int t = blockIdx.x * 256 + threadIdx.x;   // over NFRAG_H*64
    int lane = t & 63;
    int fi = t >> 6;
    int p = fi / (16 * MFRAG);
    int rem = fi - p * (16 * MFRAG);
    int cs = rem / MFRAG, mf = rem - cs * MFRAG;
    int o = mf * 16 + (lane & 15);
    int c0 = cs * 32 + (lane >> 4) * 8;
    float v[8];
    #pragma unroll
    for (int j = 0; j < 8; ++j) {
        size_t base = ((size_t)(c0 + j) * NP + p) * OP2 + o;
        float s = 0.f;
        #pragma unroll
        for (int i = 0; i < FSPLIT; ++i) s += Wcp[base + (size_t)i * S_WC];
        v[j] = s;
    }
    u32v4 hw, mw, lww;
    #pragma unroll
    for (int w = 0; w < 4; ++w)
        SPLIT3PK(v[2 * w], v[2 * w + 1], hw[w], mw[w], lww[w]);
    Whi[(size_t)fi * 64 + lane] = hw;
    Wmd[(size_t)fi * 64 + lane] = mw;
    Wlo[(size_t)fi * 64 + lane] = lww;
}

// ---------------- H[b][p][rc][o] = sum_c Wc[c*49+p][o] * I[b][c][rc] -------
// MFMA, 6-product (H feeds corner-difference cancellation -> need ~2^-24 rel).
#define KH_STEP(CUR, NXT, S)                                                  \
  {                                                                           \
    if ((S) + 1 < 16) {                                                       \
      _Pragma("unroll")                                                       \
      for (int nf = 0; nf < 2; ++nf)                                          \
        _Pragma("unroll")                                                     \
        for (int j = 0; j < 8; ++j)                                           \
          NXT[nf][j] = Ib[(size_t)(((S) + 1) * 32 + rowg * 8 + j) * IRCP2 + nf * 16]; \
    }                                                                         \
    bf16x8 bh[2], bm[2], bl[2];                                               \
    _Pragma("unroll")                                                         \
    for (int nf = 0; nf < 2; ++nf) {                                          \
      u32v4 bhw, bmw, blw;                                                    \
      _Pragma("unroll")                                                       \
      for (int w_ = 0; w_ < 4; ++w_)                                          \
        SPLIT3PK(CUR[nf][2 * w_], CUR[nf][2 * w_ + 1], bhw[w_], bmw[w_], blw[w_]); \
      bh[nf] = __builtin_bit_cast(bf16x8, bhw);                               \
      bm[nf] = __builtin_bit_cast(bf16x8, bmw);                               \
      bl[nf] = __builtin_bit_cast(bf16x8, blw);                               \
    }                                                                         \
    _Pragma("unroll")                                                         \
    for (int mf = 0; mf < MFRAG; ++mf) {                                      \
      size_t ai = (size_t)(((p * 16 + (S)) * MFRAG + mf) * 64 + lane);        \
      bf16x8 a_h = __builtin_bit_cast(bf16x8, Whi[ai]);                       \
      bf16x8 a_m = __builtin_bit_cast(bf16x8, Wmd[ai]);                       \
      bf16x8 a_l = __builtin_bit_cast(bf16x8, Wlo[ai]);                       \
      _Pragma("unroll")                                                       \
      for (int nf = 0; nf < 2; ++nf) {                                        \
        acc[mf][nf] = MFMA16(a_h, bh[nf], acc[mf][nf], 0, 0, 0);              \
        acc[mf][nf] = MFMA16(a_m, bh[nf], acc[mf][nf], 0, 0, 0);              \
        acc[mf][nf] = MFMA16(a_h, bm[nf], acc[mf][nf], 0, 0, 0);              \
        acc[mf][nf] = MFMA16(a_m, bm[nf], acc[mf][nf], 0, 0, 0);              \
        acc[mf][nf] = MFMA16(a_l, bh[nf], acc[mf][nf], 0, 0, 0);              \
        acc[mf][nf] = MFMA16(a_h, bl[nf], acc[mf][nf], 0, 0, 0);              \
      }                                                                       \
    }                                                                         \
  }

__global__ void __launch_bounds__(256, 2) k_h(const float* __restrict__ I,
                                              const u32v4* __restrict__ Whi,
                                              const u32v4* __restrict__ Wmd,
                                              const u32v4* __restrict__ Wlo,
                                              float* __restrict__ H) {
    int lane = threadIdx.x & 63;
    int w = threadIdx.x >> 6;
    int rcb = blockIdx.x, p = blockIdx.y, b = blockIdx.z;
    int col = lane & 15, rowg = lane >> 4;
    int rcw = rcb * 128 + w * 32;                 // wave's rc base
    const float* Ib = I + (size_t)b * CH * IRCP2 + rcw + col;

    f32x4 acc[MFRAG][2];
    #pragma unroll
    for (int mf = 0; mf < MFRAG; ++mf) {
        acc[mf][0] = (f32x4){0.f, 0.f, 0.f, 0.f};
        acc[mf][1] = (f32x4){0.f, 0.f, 0.f, 0.f};
    }
    float ib0[2][8], ib1[2][8];
    #pragma unroll
    for (int nf = 0; nf < 2; ++nf)
        #pragma unroll
        for (int j = 0; j < 8; ++j)
            ib0[nf][j] = Ib[(size_t)(rowg * 8 + j) * IRCP2 + nf * 16];

    for (int s = 0; s < 16; s += 2) {
        KH_STEP(ib0, ib1, s);
        KH_STEP(ib1, ib0, s + 1);
    }

    #pragma unroll
    for (int mf = 0; mf < MFRAG; ++mf)
        #pragma unroll
        for (int nf = 0; nf < 2; ++nf) {
            int rc = rcw + nf * 16 + col;
            if (rc < IRC) {
                float* hp = H + (((size_t)(b * NP + p)) * IRC + rc) * OP2
                            + mf * 16 + rowg * 4;
                *(f32x4*)hp = acc[mf][nf];
            }
        }
}

// ---------------- per-box gather + bias + argmax + outputs -----------------
__global__ void __launch_bounds__(256) k_out(const float* __restrict__ boxes,
                                             const float* __restrict__ H,
                                             const float* __restrict__ bias,
                                             float* __restrict__ out) {
    int n = blockIdx.x, b = blockIdx.y;
    int t = threadIdx.x;
    __shared__ int srs[PPOOL], sre[PPOOL], scs[PPOOL], sce[PPOOL];
    __shared__ float sinv[NP];
    __shared__ float psum[2][NO];
    __shared__ float sl[NO];
    __shared__ int smi;
    const float* bx = boxes + ((size_t)b * NBOX + n) * 4;
    if (t < PPOOL) {
        int r0 = (int)(bx[0] / 32.0f);
        int c0 = (int)(bx[1] / 32.0f);
        int r1 = (int)(bx[2] / 32.0f);
        int c1 = (int)(bx[3] / 32.0f);
        int sr = r1 - r0, sc = c1 - c0;
        srs[t] = r0 + (t * sr) / PPOOL;
        sre[t] = r0 + ((t + 1) * sr + PPOOL - 1) / PPOOL;
        scs[t] = c0 + (t * sc) / PPOOL;
        sce[t] = c0 + ((t + 1) * sc + PPOOL - 1) / PPOOL;
    }
    __syncthreads();
    if (t < NP) {
        int ph = t / PPOOL, pw = t - ph * PPOOL;
        sinv[t] = 1.0f / (float)((sre[ph] - srs[ph]) * (sce[pw] - scs[pw]));
    }
    __syncthreads();
    int o = t & 127, half = t >> 7;
    if (o < NO) {
        int p0 = half * 25, p1 = half ? NP : 25;
        float acc = 0.f;
        const float* Hb = H + (size_t)b * NP * IRC * OP2 + o;
        for (int p = p0; p < p1; ++p) {
            int ph = p / PPOOL, pw = p - ph * PPOOL;
            const float* Hp = Hb + (size_t)p * IRC * OP2;
            int re = sre[ph], rs = srs[ph], ce = sce[pw], cs = scs[pw];
            float v = Hp[(size_t)(re * IW + ce) * OP2] - Hp[(size_t)(rs * IW + ce) * OP2]
                    - Hp[(size_t)(re * IW + cs) * OP2] + Hp[(size_t)(rs * IW + cs) * OP2];
            acc += v * sinv[p];
        }
        psum[half][o] = acc;
    }
    __syncthreads();
    if (t < NO) {
        float v = psum[0][t] + psum[1][t] + bias[t];
        sl[t] = v;
        if (t >= 80)
            out[(size_t)(4 * BATCH * NBOX) + ((size_t)b * NBOX + n) * (NCLS + 1) + (t - 80)] = v;
    }
    __syncthreads();
    if (t == 0) {
        float best = sl[80]; int mi = 0;
        for (int s = 1; s <= NCLS; ++s) {
            float v = sl[80 + s];
            if (v > best) { best = v; mi = s; }
        }
        smi = mi;
    }
    __syncthreads();
    if (t < 4) out[((size_t)b * NBOX + n) * 4 + t] = sl[smi + t];
}

extern "C" void kernel_launch(void* const* d_in, const int* in_sizes, int n_in,
                              void* d_out, int out_size, void* d_ws, size_t ws_size,
                              hipStream_t stream) {
    const float* fm    = (const float*)d_in[0];
    const float* boxes = (const float*)d_in[1];
    const float* fcw   = (const float*)d_in[2];
    const float* fcb   = (const float*)d_in[3];
    const float* lw    = (const float*)d_in[4];
    const float* lb    = (const float*)d_in[5];
    const float* sw    = (const float*)d_in[6];
    const float* sb    = (const float*)d_in[7];
    float* out = (float*)d_out;

    float* ws = (float*)d_ws;
    float* I    = ws;                                        // 786,432 f
    u32v4* Ahi  = (u32v4*)(I + (size_t)BATCH * CH * IRCP2);  // 57,344 frag-words
    u32v4* Amd  = Ahi + MFRAG * NSTEP_TOT * 64;
    float* bias = (float*)(Amd + MFRAG * NSTEP_TOT * 64);    // 128 f
    float* Wcp  = bias + 128;                                // 8 * S_WC f (90 MB)
    u32v4* Whi  = (u32v4*)(Wcp + (size_t)FSPLIT * S_WC);     // 351,232 frag-words
    u32v4* Wmd  = Whi + (size_t)NFRAG_H * 64;
    u32v4* Wlo  = Wmd + (size_t)NFRAG_H * 64;
    float* H    = (float*)(Wlo + (size_t)NFRAG_H * 64);      // 7,419,392 f
    // total ws ~= 142 MB

    hipLaunchKernelGGL(k_lt, dim3(224), dim3(256), 0, stream, lw, sw, Ahi, Amd);
    hipLaunchKernelGGL(k_integral, dim3(256), dim3(256), 0, stream, fm, I);
    hipLaunchKernelGGL(k_bias, dim3(104), dim3(256), 0, stream, lw, sw, fcb, lb, sb, bias);
    hipLaunchKernelGGL(k_wc, dim3(98, FSPLIT), dim3(256), 0, stream, fcw, Ahi, Amd, Wcp);
    hipLaunchKernelGGL(k_redsplit, dim3(NFRAG_H * 64 / 256), dim3(256), 0, stream, Wcp, Whi, Wmd, Wlo);
    hipLaunchKernelGGL(k_h, dim3(6, NP, BATCH), dim3(256), 0, stream, I, Whi, Wmd, Wlo, H);
    hipLaunchKernelGGL(k_out, dim3(NBOX, BATCH), dim3(256), 0, stream, boxes, H, bias, out);
}